// Round 7
// baseline (87325.854 us; speedup 1.0000x reference)
//
#include <hip/hip_runtime.h>

typedef unsigned short u16;
typedef unsigned int u32;
typedef __attribute__((ext_vector_type(8))) short s16x8;
typedef __attribute__((ext_vector_type(4))) float f32x4;

#define MFMA_BF16 __builtin_amdgcn_mfma_f32_16x16x32_bf16
#define SCOPE_AGT __HIP_MEMORY_SCOPE_AGENT

__device__ __forceinline__ float sigf(float x) { return 1.f / (1.f + __expf(-x)); }
__device__ __forceinline__ float tanh_fast(float x) {
    float e = __expf(2.f * x);
    return 1.f - 2.f / (e + 1.f);
}
__device__ __forceinline__ u16 bf16_rn(float x) {
    u32 u = __float_as_uint(x);
    u += 0x7FFFu + ((u >> 16) & 1u);
    return (u16)(u >> 16);
}
__device__ __forceinline__ void split_store(float v, u16* __restrict__ ph,
                                            u16* __restrict__ pl, size_t off) {
    u16 h = bf16_rn(v);
    float hf = __uint_as_float(((u32)h) << 16);
    ph[off] = h;
    pl[off] = bf16_rn(v - hf);
}
__device__ __forceinline__ void mma3(f32x4& acc, s16x8 ah, s16x8 al, s16x8 wh, s16x8 wl) {
    acc = MFMA_BF16(ah, wh, acc, 0, 0, 0);
    acc = MFMA_BF16(al, wh, acc, 0, 0, 0);
    acc = MFMA_BF16(ah, wl, acc, 0, 0, 0);
}

// ---------------- weight prep: fragment-linear bf16 hi/lo ----------------
__global__ __launch_bounds__(256) void prep_w(const float* __restrict__ S1, int ld1, int K1,
                                              const float* __restrict__ S2, int ld2,
                                              u16* __restrict__ out, int NF) {
    int idx = blockIdx.x * 256 + threadIdx.x;
    int l = idx & 63;
    int sf = idx >> 6;
    int f = sf % NF;
    int s = sf / NF;
    int n = f * 16 + (l & 15);
    int kb = s * 32 + ((l >> 4) << 3);
    u16* o = out + (size_t)idx * 16;
#pragma unroll
    for (int j = 0; j < 8; ++j) {
        int k = kb + j;
        float v = (k < K1) ? S1[(size_t)n * ld1 + k] : S2[(size_t)n * ld2 + (k - K1)];
        u16 h = bf16_rn(v);
        float hf = __uint_as_float(((u32)h) << 16);
        o[j] = h;
        o[8 + j] = bf16_rn(v - hf);
    }
}

// ---------------- activation prep: f32 -> hi/lo planes ----------------
__global__ __launch_bounds__(256) void prep_act(const float* __restrict__ in,
                                                u16* __restrict__ hi, u16* __restrict__ lo,
                                                int n4) {
    int i = blockIdx.x * 256 + threadIdx.x;
    if (i >= n4) return;
    float4 v = ((const float4*)in)[i];
    float vv[4] = {v.x, v.y, v.z, v.w};
    u16 h[4], lw[4];
#pragma unroll
    for (int j = 0; j < 4; ++j) {
        h[j] = bf16_rn(vv[j]);
        float hf = __uint_as_float(((u32)h[j]) << 16);
        lw[j] = bf16_rn(vv[j] - hf);
    }
    ((ushort4*)hi)[i] = make_ushort4(h[0], h[1], h[2], h[3]);
    ((ushort4*)lo)[i] = make_ushort4(lw[0], lw[1], lw[2], lw[3]);
}

// ---------------- device-wide barrier (5 uses total) ----------------
__device__ __forceinline__ void barg(u32* __restrict__ flags, u32 k) {
    __syncthreads();
    if (threadIdx.x == 0) {
        __builtin_amdgcn_fence(__ATOMIC_RELEASE, "agent");
        __hip_atomic_store(&flags[blockIdx.x * 16], k, __ATOMIC_RELAXED, SCOPE_AGT);
    }
    if (threadIdx.x < 64) {
        for (;;) {
            u32 mn = 0xFFFFFFFFu;
#pragma unroll
            for (int j = 0; j < 4; ++j) {
                u32 v = __hip_atomic_load(&flags[((int)threadIdx.x * 4 + j) * 16],
                                          __ATOMIC_RELAXED, SCOPE_AGT);
                mn = v < mn ? v : mn;
            }
            if (__all((int)(mn >= k))) break;
            __builtin_amdgcn_s_sleep(8);
        }
    }
    if (threadIdx.x == 0) __builtin_amdgcn_fence(__ATOMIC_ACQUIRE, "agent");
    __syncthreads();
}

// ---------------- params ----------------
struct AllP {
    const u16 *Xh, *Xl, *Yh, *Yl;
    const float* ebi[4];
    const float* ebh[4];
    const float *b19, *b21, *b23, *b25, *b28, *b29, *b31, *b33, *b35;
    const u16* Wenc[4];
    const u16 *Wm1, *Wm2, *Wmu, *Wlv, *Wcg, *Wdg, *Wd1, *Wd2, *Wdo;
    u16 *HXYh, *HXYl, *H1h, *H1l, *H2h, *H2l, *muh, *mul2;
    float* CGf;
    float *outY, *muF, *lvF;
    u32* gflags;
};

// ---------------- middle-phase GEMM (thin tiles, one-shot) ----------------
template <int RF, int CF, int NS, int ACT, int WF32, int WPL>
__device__ __forceinline__ void midg(
    int row0, int col0,
    const u16* __restrict__ A1h, const u16* __restrict__ A1l, int ld1, int K1,
    const u16* __restrict__ A2h, const u16* __restrict__ A2l, int ld2,
    const u16* __restrict__ Wp, int NF,
    const float* __restrict__ b1, const float* __restrict__ b2,
    float* __restrict__ outF, int ldo,
    u16* __restrict__ Oh, u16* __restrict__ Ol, int ldop,
    int l, int lr, int lk8, int l4) {
    const s16x8* wp = (const s16x8*)Wp;
    f32x4 acc[RF][CF];
#pragma unroll
    for (int rf = 0; rf < RF; ++rf)
#pragma unroll
        for (int cf = 0; cf < CF; ++cf) acc[rf][cf] = (f32x4){0.f, 0.f, 0.f, 0.f};
#pragma unroll
    for (int s = 0; s < NS; ++s) {
        int kb = s * 32 + lk8;
        s16x8 ah[RF], al[RF];
#pragma unroll
        for (int rf = 0; rf < RF; ++rf) {
            int row = row0 + rf * 16 + lr;
            const u16 *ph, *pl2;
            size_t off;
            if (kb < K1) { ph = A1h; pl2 = A1l; off = (size_t)row * ld1 + kb; }
            else { ph = A2h; pl2 = A2l; off = (size_t)row * ld2 + (kb - K1); }
            ah[rf] = *(const s16x8*)(ph + off);
            al[rf] = *(const s16x8*)(pl2 + off);
        }
#pragma unroll
        for (int cf = 0; cf < CF; ++cf) {
            size_t wi = ((size_t)(s * NF + (col0 >> 4) + cf) * 64 + l) * 2;
            s16x8 wh = wp[wi], wl = wp[wi + 1];
#pragma unroll
            for (int rf = 0; rf < RF; ++rf) mma3(acc[rf][cf], ah[rf], al[rf], wh, wl);
        }
    }
#pragma unroll
    for (int rf = 0; rf < RF; ++rf)
#pragma unroll
        for (int cf = 0; cf < CF; ++cf) {
            int col = col0 + cf * 16 + lr;
            float bv = (b1 ? b1[col] : 0.f) + (b2 ? b2[col] : 0.f);
#pragma unroll
            for (int r = 0; r < 4; ++r) {
                float v = acc[rf][cf][r] + bv;
                if (ACT) v = tanh_fast(v);
                int row = row0 + rf * 16 + l4 + r;
                if (WF32) outF[(size_t)row * ldo + col] = v;
                if (WPL) split_store(v, Oh, Ol, (size_t)row * ldop + col);
            }
        }
}

// ---------------- the persistent kernel ----------------
__global__ __launch_bounds__(256, 2) void vae_persist(AllP P) {
    extern __shared__ u16 lds[];
    const int tid = threadIdx.x, b = blockIdx.x;
    const int wid = tid >> 6, l = tid & 63;
    const int lr = l & 15, lk8 = (l >> 4) * 8, l4 = (l >> 4) * 4;

    // ================= encoder: 128 blocks, 32 rows each, block-local =================
    if (b < 128) {
        const int scan = b >> 5, m = b & 31;
        const int T = (scan < 2) ? 64 : 100;
        const int rev = scan & 1;
        const u16* Xbh = (scan < 2) ? P.Xh : P.Yh;
        const u16* Xbl = (scan < 2) ? P.Xl : P.Yl;
        const s16x8* wp = (const s16x8*)P.Wenc[scan];
        const float* bi = P.ebi[scan];
        const float* bh = P.ebh[scan];
        const int row0 = m * 32;
        u16* Lh = lds;            // [32][264]
        u16* Ll = lds + 32 * 264;
        float cst[2][4][4] = {};
        float hs[2][4][4] = {};

        for (int t = 0; t < T; ++t) {
            int tt = rev ? (T - 1 - t) : t;
            const u16* xh = Xbh + (size_t)tt * 65536;
            const u16* xl = Xbl + (size_t)tt * 65536;
            f32x4 acc[2][4][4];
#pragma unroll
            for (int q = 0; q < 4; ++q)
#pragma unroll
                for (int cf = 0; cf < 4; ++cf) {
                    int col = q * 256 + wid * 64 + cf * 16 + lr;
                    float bv = bi[col] + bh[col];
                    f32x4 iv = {bv, bv, bv, bv};
                    acc[0][q][cf] = iv;
                    acc[1][q][cf] = iv;
                }
            // x part: k 0..63
#pragma unroll
            for (int s = 0; s < 2; ++s) {
                int kb = s * 32 + lk8;
                s16x8 ah[2], al[2];
#pragma unroll
                for (int rf = 0; rf < 2; ++rf) {
                    size_t off = (size_t)(row0 + rf * 16 + lr) * 64 + kb;
                    ah[rf] = *(const s16x8*)(xh + off);
                    al[rf] = *(const s16x8*)(xl + off);
                }
#pragma unroll
                for (int q = 0; q < 4; ++q)
#pragma unroll
                    for (int cf = 0; cf < 4; ++cf) {
                        size_t wi = ((size_t)(s * 64 + q * 16 + wid * 4 + cf) * 64 + l) * 2;
                        s16x8 wh = wp[wi], wl = wp[wi + 1];
#pragma unroll
                        for (int rf = 0; rf < 2; ++rf)
                            mma3(acc[rf][q][cf], ah[rf], al[rf], wh, wl);
                    }
            }
            // h part: k 64..319 from LDS
            if (t) {
#pragma unroll
                for (int s = 2; s < 10; ++s) {
                    int kb = s * 32 + lk8 - 64;
                    s16x8 ah[2], al[2];
#pragma unroll
                    for (int rf = 0; rf < 2; ++rf) {
                        int off = (rf * 16 + lr) * 264 + kb;
                        ah[rf] = *(const s16x8*)(Lh + off);
                        al[rf] = *(const s16x8*)(Ll + off);
                    }
#pragma unroll
                    for (int q = 0; q < 4; ++q)
#pragma unroll
                        for (int cf = 0; cf < 4; ++cf) {
                            size_t wi = ((size_t)(s * 64 + q * 16 + wid * 4 + cf) * 64 + l) * 2;
                            s16x8 wh = wp[wi], wl = wp[wi + 1];
#pragma unroll
                            for (int rf = 0; rf < 2; ++rf)
                                mma3(acc[rf][q][cf], ah[rf], al[rf], wh, wl);
                        }
                }
            }
            __syncthreads();
#pragma unroll
            for (int rf = 0; rf < 2; ++rf)
#pragma unroll
                for (int cf = 0; cf < 4; ++cf) {
                    int col = wid * 64 + cf * 16 + lr;
#pragma unroll
                    for (int r = 0; r < 4; ++r) {
                        float gi = sigf(acc[rf][0][cf][r]);
                        float gf = sigf(acc[rf][1][cf][r]);
                        float gg = tanh_fast(acc[rf][2][cf][r]);
                        float go = sigf(acc[rf][3][cf][r]);
                        float cn = gf * cst[rf][cf][r] + gi * gg;
                        float hn = go * tanh_fast(cn);
                        cst[rf][cf][r] = cn;
                        hs[rf][cf][r] += hn;
                        int lrow = rf * 16 + l4 + r;
                        u16 hh = bf16_rn(hn);
                        float hf = __uint_as_float(((u32)hh) << 16);
                        Lh[lrow * 264 + col] = hh;
                        Ll[lrow * 264 + col] = bf16_rn(hn - hf);
                    }
                }
            __syncthreads();
        }
        float sc = (scan < 2) ? (1.f / 64.f) : (1.f / 100.f);
#pragma unroll
        for (int rf = 0; rf < 2; ++rf)
#pragma unroll
            for (int cf = 0; cf < 4; ++cf)
#pragma unroll
                for (int r = 0; r < 4; ++r) {
                    int row = row0 + rf * 16 + l4 + r;
                    int col = scan * 256 + wid * 64 + cf * 16 + lr;
                    split_store(hs[rf][cf][r] * sc, P.HXYh, P.HXYl,
                                (size_t)row * 1024 + col);
                }
    }
    barg(P.gflags, 1);

    // ================= middle: e_mlp + heads + CG =================
    const int g = b * 4 + wid;
    midg<2, 2, 32, 1, 0, 1>((g & 31) * 32, (g >> 5) * 32,
                            P.HXYh, P.HXYl, 1024, 4096, P.HXYh, P.HXYl, 1024,
                            P.Wm1, 64, P.b19, nullptr, nullptr, 0,
                            P.H1h, P.H1l, 1024, l, lr, lk8, l4);
    barg(P.gflags, 2);
    midg<2, 1, 32, 1, 0, 1>((g & 31) * 32, (g >> 5) * 16,
                            P.H1h, P.H1l, 1024, 4096, P.H1h, P.H1l, 1024,
                            P.Wm2, 32, P.b21, nullptr, nullptr, 0,
                            P.H2h, P.H2l, 512, l, lr, lk8, l4);
    barg(P.gflags, 3);
    if (g < 256)
        midg<2, 1, 16, 0, 1, 1>((g & 31) * 32, (g >> 5) * 16,
                                P.H2h, P.H2l, 512, 4096, P.H2h, P.H2l, 512,
                                P.Wmu, 8, P.b23, nullptr, P.muF, 128,
                                P.muh, P.mul2, 128, l, lr, lk8, l4);
    else if (g < 512) {
        int g2 = g - 256;
        midg<2, 1, 16, 0, 1, 0>((g2 & 31) * 32, (g2 >> 5) * 16,
                                P.H2h, P.H2l, 512, 4096, P.H2h, P.H2l, 512,
                                P.Wlv, 8, P.b25, nullptr, P.lvF, 128,
                                nullptr, nullptr, 0, l, lr, lk8, l4);
    }
    barg(P.gflags, 4);
    midg<2, 4, 20, 0, 1, 0>((g & 31) * 32, (g >> 5) * 64,
                            P.HXYh, P.HXYl, 1024, 512, P.muh, P.mul2, 128,
                            P.Wcg, 128, P.b28, P.b29, P.CGf, 2048,
                            nullptr, nullptr, 0, l, lr, lk8, l4);
    barg(P.gflags, 5);
    if (b >= 64) return;

    // ================= decoder: 64 blocks, 16 rows each, block-local =================
    {
        const int row0 = b * 16;
        u16* Hh = lds;                 // [16][520]
        u16* Hl = lds + 8320;
        u16* Yh = lds + 16640;         // [16][72]
        u16* Yl = lds + 17792;
        u16* G1h = lds + 18944;        // [16][1048]
        u16* G1l = lds + 35712;
        u16* G2h = lds + 52480;        // [16][520]
        u16* G2l = lds + 60800;
        const s16x8* wpg = (const s16x8*)P.Wdg;
        const s16x8* wp1 = (const s16x8*)P.Wd1;
        const s16x8* wp2 = (const s16x8*)P.Wd2;
        const s16x8* wpo = (const s16x8*)P.Wdo;
        float cds[8][4] = {};

        // y0 = x[63] rows row0..row0+15 into Y-LDS
        for (int idx = tid; idx < 16 * 64; idx += 256) {
            int row = idx >> 6, col = idx & 63;
            size_t goff = (size_t)63 * 65536 + (size_t)(row0 + row) * 64 + col;
            Yh[row * 72 + col] = P.Xh[goff];
            Yl[row * 72 + col] = P.Xl[goff];
        }
        __syncthreads();

        for (int t = 0; t < 100; ++t) {
            // ---- gates + cell ----
            {
                f32x4 acc[4][8];
#pragma unroll
                for (int q = 0; q < 4; ++q)
#pragma unroll
                    for (int cf = 0; cf < 8; ++cf) {
                        int colc = q * 512 + wid * 128 + cf * 16 + lr;
#pragma unroll
                        for (int r = 0; r < 4; ++r)
                            acc[q][cf][r] = P.CGf[(size_t)(row0 + l4 + r) * 2048 + colc];
                    }
#pragma unroll
                for (int s = 0; s < 2; ++s) {
                    int kb = s * 32 + lk8;
                    s16x8 ah = *(const s16x8*)(Yh + lr * 72 + kb);
                    s16x8 al = *(const s16x8*)(Yl + lr * 72 + kb);
#pragma unroll
                    for (int q = 0; q < 4; ++q)
#pragma unroll
                        for (int cf = 0; cf < 8; ++cf) {
                            size_t wi = ((size_t)(s * 128 + q * 32 + wid * 8 + cf) * 64 + l) * 2;
                            mma3(acc[q][cf], ah, al, wpg[wi], wpg[wi + 1]);
                        }
                }
                if (t) {
#pragma unroll
                    for (int s = 2; s < 18; ++s) {
                        int kb = s * 32 + lk8 - 64;
                        s16x8 ah = *(const s16x8*)(Hh + lr * 520 + kb);
                        s16x8 al = *(const s16x8*)(Hl + lr * 520 + kb);
#pragma unroll
                        for (int q = 0; q < 4; ++q)
#pragma unroll
                            for (int cf = 0; cf < 8; ++cf) {
                                size_t wi = ((size_t)(s * 128 + q * 32 + wid * 8 + cf) * 64 + l) * 2;
                                mma3(acc[q][cf], ah, al, wpg[wi], wpg[wi + 1]);
                            }
                    }
                }
                __syncthreads();
#pragma unroll
                for (int cf = 0; cf < 8; ++cf) {
                    int hc = wid * 128 + cf * 16 + lr;
#pragma unroll
                    for (int r = 0; r < 4; ++r) {
                        float gi = sigf(acc[0][cf][r]);
                        float gf = sigf(acc[1][cf][r]);
                        float gg = tanh_fast(acc[2][cf][r]);
                        float go = sigf(acc[3][cf][r]);
                        float cn = gf * cds[cf][r] + gi * gg;
                        float hn = go * tanh_fast(cn);
                        cds[cf][r] = cn;
                        int row = l4 + r;
                        u16 hh = bf16_rn(hn);
                        float hf = __uint_as_float(((u32)hh) << 16);
                        Hh[row * 520 + hc] = hh;
                        Hl[row * 520 + hc] = bf16_rn(hn - hf);
                    }
                }
                __syncthreads();
            }
            // ---- mlp1: h1 = tanh(h @ Wd1 + b31) ----
            {
                f32x4 a1[16];
#pragma unroll
                for (int cf = 0; cf < 16; ++cf) a1[cf] = (f32x4){0.f, 0.f, 0.f, 0.f};
#pragma unroll
                for (int s = 0; s < 16; ++s) {
                    int kb = s * 32 + lk8;
                    s16x8 ah = *(const s16x8*)(Hh + lr * 520 + kb);
                    s16x8 al = *(const s16x8*)(Hl + lr * 520 + kb);
#pragma unroll
                    for (int cf = 0; cf < 16; ++cf) {
                        size_t wi = ((size_t)(s * 64 + wid * 16 + cf) * 64 + l) * 2;
                        mma3(a1[cf], ah, al, wp1[wi], wp1[wi + 1]);
                    }
                }
#pragma unroll
                for (int cf = 0; cf < 16; ++cf) {
                    int col = wid * 256 + cf * 16 + lr;
                    float bv = P.b31[col];
#pragma unroll
                    for (int r = 0; r < 4; ++r) {
                        float v = tanh_fast(a1[cf][r] + bv);
                        int row = l4 + r;
                        u16 hh = bf16_rn(v);
                        float hf = __uint_as_float(((u32)hh) << 16);
                        G1h[row * 1048 + col] = hh;
                        G1l[row * 1048 + col] = bf16_rn(v - hf);
                    }
                }
                __syncthreads();
            }
            // ---- mlp2: h2 = tanh(h1 @ Wd2 + b33) ----
            {
                f32x4 a2[8];
#pragma unroll
                for (int cf = 0; cf < 8; ++cf) a2[cf] = (f32x4){0.f, 0.f, 0.f, 0.f};
#pragma unroll
                for (int s = 0; s < 32; ++s) {
                    int kb = s * 32 + lk8;
                    s16x8 ah = *(const s16x8*)(G1h + lr * 1048 + kb);
                    s16x8 al = *(const s16x8*)(G1l + lr * 1048 + kb);
#pragma unroll
                    for (int cf = 0; cf < 8; ++cf) {
                        size_t wi = ((size_t)(s * 32 + wid * 8 + cf) * 64 + l) * 2;
                        mma3(a2[cf], ah, al, wp2[wi], wp2[wi + 1]);
                    }
                }
#pragma unroll
                for (int cf = 0; cf < 8; ++cf) {
                    int col = wid * 128 + cf * 16 + lr;
                    float bv = P.b33[col];
#pragma unroll
                    for (int r = 0; r < 4; ++r) {
                        float v = tanh_fast(a2[cf][r] + bv);
                        int row = l4 + r;
                        u16 hh = bf16_rn(v);
                        float hf = __uint_as_float(((u32)hh) << 16);
                        G2h[row * 520 + col] = hh;
                        G2l[row * 520 + col] = bf16_rn(v - hf);
                    }
                }
                __syncthreads();
            }
            // ---- out: y = h2 @ Wdo + b35 ----
            {
                f32x4 a3 = {0.f, 0.f, 0.f, 0.f};
#pragma unroll
                for (int s = 0; s < 16; ++s) {
                    int kb = s * 32 + lk8;
                    s16x8 ah = *(const s16x8*)(G2h + lr * 520 + kb);
                    s16x8 al = *(const s16x8*)(G2l + lr * 520 + kb);
                    size_t wi = ((size_t)(s * 4 + wid) * 64 + l) * 2;
                    mma3(a3, ah, al, wpo[wi], wpo[wi + 1]);
                }
                int col = wid * 16 + lr;
                float bv = P.b35[col];
#pragma unroll
                for (int r = 0; r < 4; ++r) {
                    float v = a3[r] + bv;
                    int row = l4 + r;
                    P.outY[(size_t)t * 65536 + (size_t)(row0 + row) * 64 + col] = v;
                    u16 hh = bf16_rn(v);
                    float hf = __uint_as_float(((u32)hh) << 16);
                    Yh[row * 72 + col] = hh;
                    Yl[row * 72 + col] = bf16_rn(v - hf);
                }
                __syncthreads();
            }
        }
    }
}

// ---------------- host ----------------
extern "C" void kernel_launch(void* const* d_in, const int* in_sizes, int n_in,
                              void* d_out, int out_size, void* d_ws, size_t ws_size,
                              hipStream_t stream) {
    (void)in_sizes; (void)n_in; (void)out_size; (void)ws_size;
    auto F = [&](int i) { return (const float*)d_in[i]; };
    const float* x = F(0);
    const float* y = F(1);
    float* out = (float*)d_out;
    char* base = (char*)d_ws;
    const size_t MB = 1ull << 20;
    const size_t KB = 1024;

    AllP P;
    P.gflags = (u32*)base;                       // 64 KB
    char* p = base + 64 * KB;
    P.HXYh = (u16*)p; p += 2 * MB;
    P.HXYl = (u16*)p; p += 2 * MB;
    P.H1h = (u16*)p; p += 2 * MB;
    P.H1l = (u16*)p; p += 2 * MB;
    P.H2h = (u16*)p; p += 1 * MB;
    P.H2l = (u16*)p; p += 1 * MB;
    P.muh = (u16*)p; p += 256 * KB;
    P.mul2 = (u16*)p; p += 256 * KB;
    P.CGf = (float*)p; p += 8 * MB;
    u16* Xh = (u16*)p; p += 8 * MB;
    u16* Xl = (u16*)p; p += 8 * MB;
    u16* Yh = (u16*)p; p += (size_t)100 * 1024 * 64 * 2;
    u16* Yl = (u16*)p; p += (size_t)100 * 1024 * 64 * 2;
    u16* W0 = (u16*)p;

    size_t wo = 0;
    auto walloc = [&](size_t elems) { u16* q = W0 + wo; wo += elems * 2; return q; };
    u16* WPX0 = walloc((size_t)1024 * 320);
    u16* WPX1 = walloc((size_t)1024 * 320);
    u16* WPE0 = walloc((size_t)1024 * 320);
    u16* WPE1 = walloc((size_t)1024 * 320);
    u16* WPM1 = walloc((size_t)1024 * 1024);
    u16* WPM2 = walloc((size_t)512 * 1024);
    u16* WPMU = walloc((size_t)128 * 512);
    u16* WPLV = walloc((size_t)128 * 512);
    u16* WPCG = walloc((size_t)2048 * 640);
    u16* WPDG = walloc((size_t)2048 * 576);
    u16* WPD1 = walloc((size_t)1024 * 512);
    u16* WPD2 = walloc((size_t)512 * 1024);
    u16* WPDO = walloc((size_t)64 * 512);

    auto prep = [&](const float* s1, int ld1, int k1, const float* s2, int ld2,
                    u16* o, int N, int KT) {
        prep_w<<<(N * KT / 8) / 256, 256, 0, stream>>>(s1, ld1, k1, s2, ld2, o, N / 16);
    };
    prep(F(2), 64, 64, F(3), 256, WPX0, 1024, 320);
    prep(F(6), 64, 64, F(7), 256, WPX1, 1024, 320);
    prep(F(10), 64, 64, F(11), 256, WPE0, 1024, 320);
    prep(F(14), 64, 64, F(15), 256, WPE1, 1024, 320);
    prep(F(18), 1024, 1024, F(18), 1024, WPM1, 1024, 1024);
    prep(F(20), 1024, 1024, F(20), 1024, WPM2, 512, 1024);
    prep(F(22), 512, 512, F(22), 512, WPMU, 128, 512);
    prep(F(24), 512, 512, F(24), 512, WPLV, 128, 512);
    prep(F(26), 704, 640, F(26), 704, WPCG, 2048, 640);
    prep(F(26) + 640, 704, 64, F(27), 512, WPDG, 2048, 576);
    prep(F(30), 512, 512, F(30), 512, WPD1, 1024, 512);
    prep(F(32), 1024, 1024, F(32), 1024, WPD2, 512, 1024);
    prep(F(34), 512, 512, F(34), 512, WPDO, 64, 512);

    prep_act<<<4096, 256, 0, stream>>>(x, Xh, Xl, 64 * 1024 * 64 / 4);
    prep_act<<<6400, 256, 0, stream>>>(y, Yh, Yl, 100 * 1024 * 64 / 4);

    hipMemsetAsync(P.gflags, 0, 64 * KB, stream);  // barrier flags

    P.Xh = Xh; P.Xl = Xl; P.Yh = Yh; P.Yl = Yl;
    const int wi[4] = {2, 6, 10, 14};
    u16* wps[4] = {WPX0, WPX1, WPE0, WPE1};
    for (int s = 0; s < 4; ++s) {
        P.Wenc[s] = wps[s];
        P.ebi[s] = F(wi[s] + 2);
        P.ebh[s] = F(wi[s] + 3);
    }
    P.Wm1 = WPM1; P.Wm2 = WPM2; P.Wmu = WPMU; P.Wlv = WPLV;
    P.Wcg = WPCG; P.Wdg = WPDG; P.Wd1 = WPD1; P.Wd2 = WPD2; P.Wdo = WPDO;
    P.b19 = F(19); P.b21 = F(21); P.b23 = F(23); P.b25 = F(25);
    P.b28 = F(28); P.b29 = F(29); P.b31 = F(31); P.b33 = F(33); P.b35 = F(35);
    P.outY = out;
    P.muF = out + (size_t)100 * 1024 * 64;
    P.lvF = P.muF + (size_t)1024 * 128;

    // decoder LDS: 138240 bytes (> 64 KB default) — opt in
    static bool attr_set = false;
    hipFuncSetAttribute((const void*)vae_persist,
                        hipFuncAttributeMaxDynamicSharedMemorySize, 147456);
    (void)attr_set;

    vae_persist<<<256, 256, 138240, stream>>>(P);
}

// Round 8
// 21745.520 us; speedup vs baseline: 4.0158x; 4.0158x over previous
//
#include <hip/hip_runtime.h>

typedef unsigned short u16;
typedef unsigned int u32;
typedef __attribute__((ext_vector_type(8))) short s16x8;
typedef __attribute__((ext_vector_type(4))) float f32x4;

#define MFMA_BF16 __builtin_amdgcn_mfma_f32_16x16x32_bf16

__device__ __forceinline__ float sigf(float x) { return 1.f / (1.f + __expf(-x)); }
__device__ __forceinline__ float tanh_fast(float x) {
    float e = __expf(2.f * x);
    return 1.f - 2.f / (e + 1.f);
}
__device__ __forceinline__ u16 bf16_rn(float x) {
    u32 u = __float_as_uint(x);
    u += 0x7FFFu + ((u >> 16) & 1u);
    return (u16)(u >> 16);
}
__device__ __forceinline__ void split_store(float v, u16* __restrict__ ph,
                                            u16* __restrict__ pl, size_t off) {
    u16 h = bf16_rn(v);
    float hf = __uint_as_float(((u32)h) << 16);
    ph[off] = h;
    pl[off] = bf16_rn(v - hf);
}
__device__ __forceinline__ void mma3(f32x4& acc, s16x8 ah, s16x8 al, s16x8 wh, s16x8 wl) {
    acc = MFMA_BF16(ah, wh, acc, 0, 0, 0);
    acc = MFMA_BF16(al, wh, acc, 0, 0, 0);
    acc = MFMA_BF16(ah, wl, acc, 0, 0, 0);
}

// ---------------- weight prep: fragment-linear bf16 hi/lo ----------------
__global__ __launch_bounds__(256) void prep_w(const float* __restrict__ S1, int ld1, int K1,
                                              const float* __restrict__ S2, int ld2,
                                              u16* __restrict__ out, int NF) {
    int idx = blockIdx.x * 256 + threadIdx.x;
    int l = idx & 63;
    int sf = idx >> 6;
    int f = sf % NF;
    int s = sf / NF;
    int n = f * 16 + (l & 15);
    int kb = s * 32 + ((l >> 4) << 3);
    u16* o = out + (size_t)idx * 16;
#pragma unroll
    for (int j = 0; j < 8; ++j) {
        int k = kb + j;
        float v = (k < K1) ? S1[(size_t)n * ld1 + k] : S2[(size_t)n * ld2 + (k - K1)];
        u16 h = bf16_rn(v);
        float hf = __uint_as_float(((u32)h) << 16);
        o[j] = h;
        o[8 + j] = bf16_rn(v - hf);
    }
}

// ---------------- activation prep: f32 -> hi/lo planes ----------------
__global__ __launch_bounds__(256) void prep_act(const float* __restrict__ in,
                                                u16* __restrict__ hi, u16* __restrict__ lo,
                                                int n4) {
    int i = blockIdx.x * 256 + threadIdx.x;
    if (i >= n4) return;
    float4 v = ((const float4*)in)[i];
    float vv[4] = {v.x, v.y, v.z, v.w};
    u16 h[4], lw[4];
#pragma unroll
    for (int j = 0; j < 4; ++j) {
        h[j] = bf16_rn(vv[j]);
        float hf = __uint_as_float(((u32)h[j]) << 16);
        lw[j] = bf16_rn(vv[j] - hf);
    }
    ((ushort4*)hi)[i] = make_ushort4(h[0], h[1], h[2], h[3]);
    ((ushort4*)lo)[i] = make_ushort4(lw[0], lw[1], lw[2], lw[3]);
}

// ---------------- generic GEMM: block = 64 rows x (CF*16) cols, 4 waves split rows ----------------
// Waves share the column slice -> W fragments hit L1. Full K unroll for load pipelining.
template <int CTBITS, int CF, int NS, int ACT, int WF32, int WFRAG, int WPL>
__global__ __launch_bounds__(256, 2) void gemm_k(
    const u16* __restrict__ A1h, const u16* __restrict__ A1l, int ld1, int K1,
    const u16* __restrict__ A2h, const u16* __restrict__ A2l, int ld2,
    const u16* __restrict__ Wp, int NF,
    const float* __restrict__ b1, const float* __restrict__ b2,
    float* __restrict__ outF, int ldo, float* __restrict__ outFrag,
    u16* __restrict__ Oh, u16* __restrict__ Ol, int ldop) {
    const int tid = threadIdx.x, b = blockIdx.x;
    const int wid = tid >> 6, l = tid & 63;
    const int lr = l & 15, lk8 = (l >> 4) * 8, l4 = (l >> 4) * 4;
    const int ct = b & ((1 << CTBITS) - 1), rt = b >> CTBITS;
    const int row0 = rt * 64 + wid * 16;
    const int col0 = ct * CF * 16;
    const int fbase = ct * CF;
    const s16x8* wp = (const s16x8*)Wp;
    const int rowA = row0 + lr;

    f32x4 acc[CF] = {};
#pragma unroll
    for (int s = 0; s < NS; ++s) {
        int kb = s * 32 + lk8;
        const u16 *ph, *pl2;
        size_t off;
        if (kb < K1) { ph = A1h; pl2 = A1l; off = (size_t)rowA * ld1 + kb; }
        else { ph = A2h; pl2 = A2l; off = (size_t)rowA * ld2 + (kb - K1); }
        s16x8 ah = *(const s16x8*)(ph + off), al = *(const s16x8*)(pl2 + off);
#pragma unroll
        for (int cf = 0; cf < CF; ++cf) {
            size_t wi = ((size_t)(s * NF + fbase + cf) * 64 + l) * 2;
            mma3(acc[cf], ah, al, wp[wi], wp[wi + 1]);
        }
    }
#pragma unroll
    for (int cf = 0; cf < CF; ++cf) {
        int col = col0 + cf * 16 + lr;
        float bv = (b1 ? b1[col] : 0.f) + (b2 ? b2[col] : 0.f);
        f32x4 v4;
#pragma unroll
        for (int r = 0; r < 4; ++r) {
            float v = acc[cf][r] + bv;
            if (ACT) v = tanh_fast(v);
            v4[r] = v;
            int row = row0 + l4 + r;
            if (WF32) outF[(size_t)row * ldo + col] = v;
            if (WPL) split_store(v, Oh, Ol, (size_t)row * ldop + col);
        }
        if (WFRAG) {
            int frag = (row0 >> 4) * 128 + ((col0 + cf * 16) >> 4);
            *(f32x4*)(outFrag + (size_t)frag * 256 + l * 4) = v4;
        }
    }
}

// ---------------- encoder gates + cell ----------------
struct EncP {
    const u16* Wp[4];
    const float* ebi[4];
    const float* ebh[4];
    u16* Hh[4];
    u16* Hl[4];
    float* C[4];
    float* hsum[4];
    const u16 *xh, *xl, *yh, *yl;
};

template <int NS>
__global__ __launch_bounds__(256, 2) void enc_gates(EncP p, int t, int scanoff, int slshift) {
    const int tid = threadIdx.x, b = blockIdx.x;
    const int wid = tid >> 6, l = tid & 63;
    const int lr = l & 15, lk8 = (l >> 4) * 8, l4 = (l >> 4) * 4;
    const int slice = b & ((1 << slshift) - 1);
    const int scan = (slice >> 2) + scanoff;
    const int ct = slice & 3;
    const int rt = b >> slshift;

    const int T = (scan < 2) ? 64 : 100;
    const int tt = (scan & 1) ? (T - 1 - t) : t;
    const u16* __restrict__ Xh = ((scan < 2) ? p.xh : p.yh) + (size_t)tt * 65536;
    const u16* __restrict__ Xl = ((scan < 2) ? p.xl : p.yl) + (size_t)tt * 65536;
    const u16* __restrict__ Hch = p.Hh[scan] + (size_t)(t & 1) * 262144;
    const u16* __restrict__ Hcl = p.Hl[scan] + (size_t)(t & 1) * 262144;
    u16* __restrict__ Hnh = p.Hh[scan] + (size_t)((t + 1) & 1) * 262144;
    u16* __restrict__ Hnl = p.Hl[scan] + (size_t)((t + 1) & 1) * 262144;
    float* __restrict__ Cs = p.C[scan];
    const s16x8* __restrict__ wp = (const s16x8*)p.Wp[scan];
    const float* __restrict__ bi = p.ebi[scan];
    const float* __restrict__ bh = p.ebh[scan];
    float* __restrict__ hs = p.hsum[scan];

    const int row0 = rt * 64 + wid * 16;
    const int rowA = row0 + lr;
    const int hc0 = ct * 64;

    f32x4 acc[4][4];
#pragma unroll
    for (int q = 0; q < 4; ++q)
#pragma unroll
        for (int cf = 0; cf < 4; ++cf) {
            int col = q * 256 + hc0 + cf * 16 + lr;
            float bv = bi[col] + bh[col];
            acc[q][cf] = (f32x4){bv, bv, bv, bv};
        }
#pragma unroll
    for (int s = 0; s < NS; ++s) {
        int kb = s * 32 + lk8;
        const u16 *ph, *pl2;
        size_t off;
        if (kb < 64) { ph = Xh; pl2 = Xl; off = (size_t)rowA * 64 + kb; }
        else { ph = Hch; pl2 = Hcl; off = (size_t)rowA * 256 + (kb - 64); }
        s16x8 ah = *(const s16x8*)(ph + off), al = *(const s16x8*)(pl2 + off);
#pragma unroll
        for (int q = 0; q < 4; ++q)
#pragma unroll
            for (int cf = 0; cf < 4; ++cf) {
                size_t wi = ((size_t)(s * 64 + q * 16 + ct * 4 + cf) * 64 + l) * 2;
                mma3(acc[q][cf], ah, al, wp[wi], wp[wi + 1]);
            }
    }
#pragma unroll
    for (int cf = 0; cf < 4; ++cf) {
        int hc = hc0 + cf * 16 + lr;
#pragma unroll
        for (int r = 0; r < 4; ++r) {
            int row = row0 + l4 + r;
            size_t co = (size_t)row * 256 + hc;
            float gi = sigf(acc[0][cf][r]);
            float gf = sigf(acc[1][cf][r]);
            float gg = tanh_fast(acc[2][cf][r]);
            float go = sigf(acc[3][cf][r]);
            float cn = gf * Cs[co] + gi * gg;
            float hn = go * tanh_fast(cn);
            Cs[co] = cn;
            split_store(hn, Hnh, Hnl, co);
            hs[(size_t)row * 1024 + hc] += hn;
        }
    }
}

// ---------------- decoder gates + cell (CG fragment-linear f32x4) ----------------
template <int NS>
__global__ __launch_bounds__(256, 2) void dec_gates(
    const u16* __restrict__ yph, const u16* __restrict__ ypl,
    const u16* __restrict__ Hch, const u16* __restrict__ Hcl,
    const u16* __restrict__ Wpu, const float* __restrict__ CGF,
    u16* __restrict__ Hnh, u16* __restrict__ Hnl, float* __restrict__ Cs) {
    const int tid = threadIdx.x, b = blockIdx.x;
    const int wid = tid >> 6, l = tid & 63;
    const int lr = l & 15, lk8 = (l >> 4) * 8, l4 = (l >> 4) * 4;
    const int ct = b & 7, rt = b >> 3;
    const int row0 = rt * 64 + wid * 16;
    const int rowA = row0 + lr;
    const int rowtile = rt * 4 + wid;
    const s16x8* wp = (const s16x8*)Wpu;

    f32x4 acc[4][4];
#pragma unroll
    for (int q = 0; q < 4; ++q)
#pragma unroll
        for (int cf = 0; cf < 4; ++cf) {
            int frag = rowtile * 128 + q * 32 + ct * 4 + cf;
            acc[q][cf] = *(const f32x4*)(CGF + (size_t)frag * 256 + l * 4);
        }
#pragma unroll
    for (int s = 0; s < NS; ++s) {
        int kb = s * 32 + lk8;
        const u16 *ph, *pl2;
        size_t off;
        if (kb < 64) { ph = yph; pl2 = ypl; off = (size_t)rowA * 64 + kb; }
        else { ph = Hch; pl2 = Hcl; off = (size_t)rowA * 512 + (kb - 64); }
        s16x8 ah = *(const s16x8*)(ph + off), al = *(const s16x8*)(pl2 + off);
#pragma unroll
        for (int q = 0; q < 4; ++q)
#pragma unroll
            for (int cf = 0; cf < 4; ++cf) {
                size_t wi = ((size_t)(s * 128 + q * 32 + ct * 4 + cf) * 64 + l) * 2;
                mma3(acc[q][cf], ah, al, wp[wi], wp[wi + 1]);
            }
    }
#pragma unroll
    for (int cf = 0; cf < 4; ++cf) {
        int hc = ct * 64 + cf * 16 + lr;
#pragma unroll
        for (int r = 0; r < 4; ++r) {
            int row = row0 + l4 + r;
            size_t co = (size_t)row * 512 + hc;
            float gi = sigf(acc[0][cf][r]);
            float gf = sigf(acc[1][cf][r]);
            float gg = tanh_fast(acc[2][cf][r]);
            float go = sigf(acc[3][cf][r]);
            float cn = gf * Cs[co] + gi * gg;
            float hn = go * tanh_fast(cn);
            Cs[co] = cn;
            split_store(hn, Hnh, Hnl, co);
        }
    }
}

// ---------------- finalize: hsum -> HXY planes ----------------
__global__ __launch_bounds__(256) void finalize_enc(const float* __restrict__ hs,
                                                    u16* __restrict__ Hh,
                                                    u16* __restrict__ Hl) {
    int i = blockIdx.x * 256 + threadIdx.x;  // 1024*1024
    int col = i & 1023;
    float v = hs[i] * ((col < 512) ? (1.f / 64.f) : (1.f / 100.f));
    split_store(v, Hh, Hl, (size_t)i);
}

// ---------------- host ----------------
extern "C" void kernel_launch(void* const* d_in, const int* in_sizes, int n_in,
                              void* d_out, int out_size, void* d_ws, size_t ws_size,
                              hipStream_t stream) {
    (void)in_sizes; (void)n_in; (void)out_size; (void)ws_size;
    auto F = [&](int i) { return (const float*)d_in[i]; };
    const float* x = F(0);
    const float* y = F(1);
    float* out = (float*)d_out;
    char* base = (char*)d_ws;
    const size_t MB = 1ull << 20;
    const size_t KB = 1024;

    // ---- workspace ----
    float* hsumf = (float*)base;                 // 4 MB (encoder)  -> CGF later
    float* CGF = (float*)base;                   // 8 MB (decoder, frag-linear)
    float* encC = (float*)(base + 8 * MB);       // 4 MB
    float* decC = (float*)(base + 12 * MB);      // 2 MB
    char* p = base + 14 * MB;
    u16* encHh = (u16*)p; p += 4 * MB;           // [4][2][1024*256]
    u16* encHl = (u16*)p; p += 4 * MB;
    u16* decHh = (u16*)p; p += 2 * MB;           // [2][1024*512]
    u16* decHl = (u16*)p; p += 2 * MB;
    u16* HXYh = (u16*)p; p += 2 * MB;
    u16* HXYl = (u16*)p; p += 2 * MB;
    u16* H1h = (u16*)p; p += 2 * MB;
    u16* H1l = (u16*)p; p += 2 * MB;
    u16* H2h = (u16*)p; p += 1 * MB;
    u16* H2l = (u16*)p; p += 1 * MB;
    u16* muh = (u16*)p; p += 256 * KB;
    u16* mul2 = (u16*)p; p += 256 * KB;
    u16* Ydh = (u16*)p; p += 128 * KB;
    u16* Ydl = (u16*)p; p += 128 * KB;
    u16* Xh = (u16*)p; p += 8 * MB;
    u16* Xl = (u16*)p; p += 8 * MB;
    u16* Yh = (u16*)p; p += (size_t)100 * 1024 * 64 * 2;
    u16* Yl = (u16*)p; p += (size_t)100 * 1024 * 64 * 2;
    u16* W0 = (u16*)p;

    size_t wo = 0;
    auto walloc = [&](size_t elems) { u16* q = W0 + wo; wo += elems * 2; return q; };
    u16* WPX0 = walloc((size_t)1024 * 320);
    u16* WPX1 = walloc((size_t)1024 * 320);
    u16* WPE0 = walloc((size_t)1024 * 320);
    u16* WPE1 = walloc((size_t)1024 * 320);
    u16* WPM1 = walloc((size_t)1024 * 1024);
    u16* WPM2 = walloc((size_t)512 * 1024);
    u16* WPMU = walloc((size_t)128 * 512);
    u16* WPLV = walloc((size_t)128 * 512);
    u16* WPCG = walloc((size_t)2048 * 640);
    u16* WPDG = walloc((size_t)2048 * 576);
    u16* WPD1 = walloc((size_t)1024 * 512);
    u16* WPD2 = walloc((size_t)512 * 1024);
    u16* WPDO = walloc((size_t)64 * 512);

    auto prep = [&](const float* s1, int ld1, int k1, const float* s2, int ld2,
                    u16* o, int N, int KT) {
        prep_w<<<(N * KT / 8) / 256, 256, 0, stream>>>(s1, ld1, k1, s2, ld2, o, N / 16);
    };
    prep(F(2), 64, 64, F(3), 256, WPX0, 1024, 320);
    prep(F(6), 64, 64, F(7), 256, WPX1, 1024, 320);
    prep(F(10), 64, 64, F(11), 256, WPE0, 1024, 320);
    prep(F(14), 64, 64, F(15), 256, WPE1, 1024, 320);
    prep(F(18), 1024, 1024, F(18), 1024, WPM1, 1024, 1024);
    prep(F(20), 1024, 1024, F(20), 1024, WPM2, 512, 1024);
    prep(F(22), 512, 512, F(22), 512, WPMU, 128, 512);
    prep(F(24), 512, 512, F(24), 512, WPLV, 128, 512);
    prep(F(26), 704, 640, F(26), 704, WPCG, 2048, 640);
    prep(F(26) + 640, 704, 64, F(27), 512, WPDG, 2048, 576);
    prep(F(30), 512, 512, F(30), 512, WPD1, 1024, 512);
    prep(F(32), 1024, 1024, F(32), 1024, WPD2, 512, 1024);
    prep(F(34), 512, 512, F(34), 512, WPDO, 64, 512);

    prep_act<<<4096, 256, 0, stream>>>(x, Xh, Xl, 64 * 1024 * 64 / 4);
    prep_act<<<6400, 256, 0, stream>>>(y, Yh, Yl, 100 * 1024 * 64 / 4);

    // zero: hsum(4MB) + encC(4MB @8MB) + decC(2MB @12MB) = first 14 MB
    hipMemsetAsync(base, 0, 14 * MB, stream);

    EncP ep;
    const int wi[4] = {2, 6, 10, 14};
    u16* wps[4] = {WPX0, WPX1, WPE0, WPE1};
    for (int s = 0; s < 4; ++s) {
        ep.Wp[s] = wps[s];
        ep.ebi[s] = F(wi[s] + 2);
        ep.ebh[s] = F(wi[s] + 3);
        ep.Hh[s] = encHh + (size_t)s * 2 * 1024 * 256 / 2;  // elems: s*2*262144/... careful
        ep.Hl[s] = encHl + (size_t)s * 2 * 262144 / 2;
        ep.C[s] = encC + (size_t)s * 262144;
        ep.hsum[s] = hsumf + (size_t)s * 256;
    }
    // fix: per-scan H plane stride = 2 buffers * 1024*256 elems = 524288 u16
    for (int s = 0; s < 4; ++s) {
        ep.Hh[s] = encHh + (size_t)s * 524288;
        ep.Hl[s] = encHl + (size_t)s * 524288;
    }
    ep.xh = Xh; ep.xl = Xl; ep.yh = Yh; ep.yl = Yl;

    // ---- encoder ----
    enc_gates<2><<<256, 256, 0, stream>>>(ep, 0, 0, 4);
    for (int t = 1; t < 64; ++t)
        enc_gates<10><<<256, 256, 0, stream>>>(ep, t, 0, 4);
    {
        // t=64..99: only scans 2,3 — but t=64 for scans 2/3 is a regular step (t>0)
        for (int t = 64; t < 100; ++t)
            enc_gates<10><<<128, 256, 0, stream>>>(ep, t, 2, 3);
    }

    finalize_enc<<<4096, 256, 0, stream>>>(hsumf, HXYh, HXYl);

    float* muF = out + (size_t)100 * 1024 * 64;
    float* lvF = muF + (size_t)1024 * 128;

    // e_mlp1: [1024,1024]x[1024,1024]
    gemm_k<4, 4, 32, 1, 0, 0, 1><<<256, 256, 0, stream>>>(
        HXYh, HXYl, 1024, 4096, HXYh, HXYl, 1024, WPM1, 64,
        F(19), nullptr, nullptr, 0, nullptr, H1h, H1l, 1024);
    // e_mlp2: [1024,1024]x[512,1024]
    gemm_k<3, 4, 32, 1, 0, 0, 1><<<128, 256, 0, stream>>>(
        H1h, H1l, 1024, 4096, H1h, H1l, 1024, WPM2, 32,
        F(21), nullptr, nullptr, 0, nullptr, H2h, H2l, 512);
    // heads
    gemm_k<1, 4, 16, 0, 1, 0, 1><<<32, 256, 0, stream>>>(
        H2h, H2l, 512, 4096, H2h, H2l, 512, WPMU, 8,
        F(23), nullptr, muF, 128, nullptr, muh, mul2, 128);
    gemm_k<1, 4, 16, 0, 1, 0, 0><<<32, 256, 0, stream>>>(
        H2h, H2l, 512, 4096, H2h, H2l, 512, WPLV, 8,
        F(25), nullptr, lvF, 128, nullptr, nullptr, nullptr, 0);
    // CG: [h_x | z] @ Wih[:, :640]^T + biases -> fragment-linear f32 (overwrites hsum)
    gemm_k<4, 8, 20, 0, 0, 1, 0><<<256, 256, 0, stream>>>(
        HXYh, HXYl, 1024, 512, muh, mul2, 128, WPCG, 128,
        F(28), F(29), nullptr, 0, CGF, nullptr, nullptr, 0);

    // ---- decoder ----
    for (int t = 0; t < 100; ++t) {
        const u16* yph = (t == 0) ? (Xh + (size_t)63 * 65536) : Ydh;
        const u16* ypl = (t == 0) ? (Xl + (size_t)63 * 65536) : Ydl;
        const u16* Hch = decHh + (size_t)(t & 1) * 524288;
        const u16* Hcl = decHl + (size_t)(t & 1) * 524288;
        u16* Hnh = decHh + (size_t)((t + 1) & 1) * 524288;
        u16* Hnl = decHl + (size_t)((t + 1) & 1) * 524288;
        if (t == 0)
            dec_gates<2><<<128, 256, 0, stream>>>(yph, ypl, Hch, Hcl, WPDG, CGF,
                                                  Hnh, Hnl, decC);
        else
            dec_gates<18><<<128, 256, 0, stream>>>(yph, ypl, Hch, Hcl, WPDG, CGF,
                                                   Hnh, Hnl, decC);
        // d_mlp1: [1024,512]x[1024,512]
        gemm_k<4, 4, 16, 1, 0, 0, 1><<<256, 256, 0, stream>>>(
            Hnh, Hnl, 512, 4096, Hnh, Hnl, 512, WPD1, 64,
            F(31), nullptr, nullptr, 0, nullptr, H1h, H1l, 1024);
        // d_mlp2
        gemm_k<3, 4, 32, 1, 0, 0, 1><<<128, 256, 0, stream>>>(
            H1h, H1l, 1024, 4096, H1h, H1l, 1024, WPD2, 32,
            F(33), nullptr, nullptr, 0, nullptr, H2h, H2l, 512);
        // d_out
        gemm_k<0, 4, 16, 0, 1, 0, 1><<<16, 256, 0, stream>>>(
            H2h, H2l, 512, 4096, H2h, H2l, 512, WPDO, 4,
            F(35), nullptr, out + (size_t)t * 65536, 64, nullptr, Ydh, Ydl, 64);
    }
}

// Round 9
// 9842.741 us; speedup vs baseline: 8.8721x; 2.2093x over previous
//
#include <hip/hip_runtime.h>

typedef unsigned short u16;
typedef unsigned int u32;
typedef __attribute__((ext_vector_type(8))) short s16x8;
typedef __attribute__((ext_vector_type(4))) float f32x4;

#define MFMA_BF16 __builtin_amdgcn_mfma_f32_16x16x32_bf16

__device__ __forceinline__ float sigf(float x) { return 1.f / (1.f + __expf(-x)); }
__device__ __forceinline__ float tanh_fast(float x) {
    float e = __expf(2.f * x);
    return 1.f - 2.f / (e + 1.f);
}
__device__ __forceinline__ u16 bf16_rn(float x) {
    u32 u = __float_as_uint(x);
    u += 0x7FFFu + ((u >> 16) & 1u);
    return (u16)(u >> 16);
}
__device__ __forceinline__ void split_store(float v, u16* __restrict__ ph,
                                            u16* __restrict__ pl, size_t off) {
    u16 h = bf16_rn(v);
    float hf = __uint_as_float(((u32)h) << 16);
    ph[off] = h;
    pl[off] = bf16_rn(v - hf);
}
__device__ __forceinline__ void mma3(f32x4& acc, s16x8 ah, s16x8 al, s16x8 wh, s16x8 wl) {
    acc = MFMA_BF16(ah, wh, acc, 0, 0, 0);
    acc = MFMA_BF16(al, wh, acc, 0, 0, 0);
    acc = MFMA_BF16(ah, wl, acc, 0, 0, 0);
}
// async global->LDS, 16B per lane; lds base must be wave-uniform
__device__ __forceinline__ void gll16(const u16* g, u16* l) {
    __builtin_amdgcn_global_load_lds(
        (const __attribute__((address_space(1))) u32*)g,
        (__attribute__((address_space(3))) u32*)l, 16, 0, 0);
}

// ---------------- weight prep: fragment blocks, plane-separated ----------------
// frag-block u = s*NF+f: u16[1024]: hi[64 lanes][8] at +0, lo at +512.
__global__ __launch_bounds__(256) void prep_w(const float* __restrict__ S1, int ld1, int K1,
                                              const float* __restrict__ S2, int ld2,
                                              u16* __restrict__ out, int NF) {
    int idx = blockIdx.x * 256 + threadIdx.x;
    int l = idx & 63;
    int u = idx >> 6;
    int f = u % NF;
    int s = u / NF;
    int n = f * 16 + (l & 15);
    int kb = s * 32 + ((l >> 4) << 3);
    u16* o = out + (size_t)u * 1024 + l * 8;
#pragma unroll
    for (int j = 0; j < 8; ++j) {
        int k = kb + j;
        float v = (k < K1) ? S1[(size_t)n * ld1 + k] : S2[(size_t)n * ld2 + (k - K1)];
        u16 h = bf16_rn(v);
        float hf = __uint_as_float(((u32)h) << 16);
        o[j] = h;
        o[512 + j] = bf16_rn(v - hf);
    }
}

// ---------------- activation prep: f32 -> hi/lo planes ----------------
__global__ __launch_bounds__(256) void prep_act(const float* __restrict__ in,
                                                u16* __restrict__ hi, u16* __restrict__ lo,
                                                int n4) {
    int i = blockIdx.x * 256 + threadIdx.x;
    if (i >= n4) return;
    float4 v = ((const float4*)in)[i];
    float vv[4] = {v.x, v.y, v.z, v.w};
    u16 h[4], lw[4];
#pragma unroll
    for (int j = 0; j < 4; ++j) {
        h[j] = bf16_rn(vv[j]);
        float hf = __uint_as_float(((u32)h[j]) << 16);
        lw[j] = bf16_rn(vv[j] - hf);
    }
    ((ushort4*)hi)[i] = make_ushort4(h[0], h[1], h[2], h[3]);
    ((ushort4*)lo)[i] = make_ushort4(lw[0], lw[1], lw[2], lw[3]);
}

// ---------------- generic LDS-staged GEMM ----------------
// block: 64 rows (4 waves x 16) x CF*16 cols; ct = b % NCTB (XCD affinity in low bits).
// Weight tile (CF frag-blocks, contiguous) staged via global_load_lds, double-buffered.
template <int CF, int NCTB, int NS, int ACT, int WF32, int WFRAG, int WPL>
__global__ __launch_bounds__(256) void gemm_lds(
    const u16* __restrict__ A1h, const u16* __restrict__ A1l, int ld1, int K1,
    const u16* __restrict__ A2h, const u16* __restrict__ A2l, int ld2,
    const u16* __restrict__ Wp, int NF,
    const float* __restrict__ b1, const float* __restrict__ b2,
    float* __restrict__ outF, int ldo, float* __restrict__ outFrag,
    u16* __restrict__ Oh, u16* __restrict__ Ol, int ldop) {
    __shared__ u16 sm[2][CF * 1024];
    const int tid = threadIdx.x, b = blockIdx.x;
    const int wid = tid >> 6, l = tid & 63;
    const int lr = l & 15, lk8 = (l >> 4) * 8, l4 = (l >> 4) * 4;
    const int ct = b % NCTB, rt = b / NCTB;
    const int row0 = rt * 64 + wid * 16;
    const int rowA = row0 + lr;
    const int fbase = ct * CF;

    auto stage = [&](int s, int buf) {
        const u16* wsrc = Wp + (size_t)(s * NF + fbase) * 1024;
#pragma unroll
        for (int i = 0; i < CF / 2; ++i)
            gll16(wsrc + i * 2048 + wid * 512 + l * 8,
                  &sm[buf][i * 2048 + wid * 512]);
    };

    f32x4 acc[CF] = {};
    stage(0, 0);
    __syncthreads();
    for (int s = 0; s < NS; ++s) {
        if (s + 1 < NS) stage(s + 1, (s + 1) & 1);
        int kb = s * 32 + lk8;
        const u16 *ph, *pl2;
        size_t off;
        if (kb < K1) { ph = A1h; pl2 = A1l; off = (size_t)rowA * ld1 + kb; }
        else { ph = A2h; pl2 = A2l; off = (size_t)rowA * ld2 + (kb - K1); }
        s16x8 ah = *(const s16x8*)(ph + off), al = *(const s16x8*)(pl2 + off);
        const u16* cur = sm[s & 1];
#pragma unroll
        for (int cf = 0; cf < CF; ++cf) {
            s16x8 wh = *(const s16x8*)(cur + cf * 1024 + l * 8);
            s16x8 wl = *(const s16x8*)(cur + cf * 1024 + 512 + l * 8);
            mma3(acc[cf], ah, al, wh, wl);
        }
        __syncthreads();
    }
#pragma unroll
    for (int cf = 0; cf < CF; ++cf) {
        int col = (fbase + cf) * 16 + lr;
        float bv = (b1 ? b1[col] : 0.f) + (b2 ? b2[col] : 0.f);
        f32x4 v4;
#pragma unroll
        for (int r = 0; r < 4; ++r) {
            float v = acc[cf][r] + bv;
            if (ACT) v = tanh_fast(v);
            v4[r] = v;
            int row = row0 + l4 + r;
            if (WF32) outF[(size_t)row * ldo + col] = v;
            if (WPL) split_store(v, Oh, Ol, (size_t)row * ldop + col);
        }
        if (WFRAG) {
            int frag = (rt * 4 + wid) * 128 + fbase + cf;
            *(f32x4*)(outFrag + (size_t)frag * 256 + l * 4) = v4;
        }
    }
}

// ---------------- decoder gates + cell, LDS-staged ----------------
// grid 256: ct = b&15 (32-col slice for all 4 gates), rt = b>>4.
template <int NS>
__global__ __launch_bounds__(256) void dec_gates_lds(
    const u16* __restrict__ yph, const u16* __restrict__ ypl,
    const u16* __restrict__ Hch, const u16* __restrict__ Hcl,
    const u16* __restrict__ Wp, const float* __restrict__ CGF,
    u16* __restrict__ Hnh, u16* __restrict__ Hnl, float* __restrict__ Cs) {
    __shared__ u16 sm[2][8192];  // 4 gate-chunks x 2 frags x 1024
    const int tid = threadIdx.x, b = blockIdx.x;
    const int wid = tid >> 6, l = tid & 63;
    const int lr = l & 15, lk8 = (l >> 4) * 8, l4 = (l >> 4) * 4;
    const int ct = b & 15, rt = b >> 4;
    const int row0 = rt * 64 + wid * 16;
    const int rowA = row0 + lr;
    const int rowtile = rt * 4 + wid;
    const int hc0 = ct * 32;

    auto stage = [&](int s, int buf) {
#pragma unroll
        for (int q = 0; q < 4; ++q)
            gll16(Wp + (size_t)(s * 128 + q * 32 + ct * 2) * 1024 + wid * 512 + l * 8,
                  &sm[buf][q * 2048 + wid * 512]);
    };

    f32x4 acc[4][2];
#pragma unroll
    for (int q = 0; q < 4; ++q)
#pragma unroll
        for (int cf = 0; cf < 2; ++cf) {
            int frag = rowtile * 128 + q * 32 + ct * 2 + cf;
            acc[q][cf] = *(const f32x4*)(CGF + (size_t)frag * 256 + l * 4);
        }

    stage(0, 0);
    __syncthreads();
    for (int s = 0; s < NS; ++s) {
        if (s + 1 < NS) stage(s + 1, (s + 1) & 1);
        int kb = s * 32 + lk8;
        const u16 *ph, *pl2;
        size_t off;
        if (kb < 64) { ph = yph; pl2 = ypl; off = (size_t)rowA * 64 + kb; }
        else { ph = Hch; pl2 = Hcl; off = (size_t)rowA * 512 + (kb - 64); }
        s16x8 ah = *(const s16x8*)(ph + off), al = *(const s16x8*)(pl2 + off);
        const u16* cur = sm[s & 1];
#pragma unroll
        for (int q = 0; q < 4; ++q)
#pragma unroll
            for (int cf = 0; cf < 2; ++cf) {
                s16x8 wh = *(const s16x8*)(cur + q * 2048 + cf * 1024 + l * 8);
                s16x8 wl = *(const s16x8*)(cur + q * 2048 + cf * 1024 + 512 + l * 8);
                mma3(acc[q][cf], ah, al, wh, wl);
            }
        __syncthreads();
    }
#pragma unroll
    for (int cf = 0; cf < 2; ++cf) {
        int hc = hc0 + cf * 16 + lr;
#pragma unroll
        for (int r = 0; r < 4; ++r) {
            int row = row0 + l4 + r;
            size_t co = (size_t)row * 512 + hc;
            float gi = sigf(acc[0][cf][r]);
            float gf = sigf(acc[1][cf][r]);
            float gg = tanh_fast(acc[2][cf][r]);
            float go = sigf(acc[3][cf][r]);
            float cn = gf * Cs[co] + gi * gg;
            float hn = go * tanh_fast(cn);
            Cs[co] = cn;
            split_store(hn, Hnh, Hnl, co);
        }
    }
}

// ---------------- encoder gates + cell (direct loads, XCD-affine) ----------------
struct EncP {
    const u16* Wp[4];
    const float* ebi[4];
    const float* ebh[4];
    u16* Hh[4];
    u16* Hl[4];
    float* C[4];
    float* hsum[4];
    const u16 *xh, *xl, *yh, *yl;
};

template <int NS>
__global__ __launch_bounds__(256) void enc_gates(EncP p, int t, int smode) {
    const int tid = threadIdx.x, b = blockIdx.x;
    const int wid = tid >> 6, l = tid & 63;
    const int lr = l & 15, lk8 = (l >> 4) * 8, l4 = (l >> 4) * 4;
    int scan, ct, rt;
    if (smode == 0) { scan = b & 3; ct = (b >> 2) & 3; rt = b >> 4; }
    else { scan = 2 + (b & 1); ct = (b >> 1) & 3; rt = b >> 3; }

    const int T = (scan < 2) ? 64 : 100;
    const int tt = (scan & 1) ? (T - 1 - t) : t;
    const u16* __restrict__ Xh = ((scan < 2) ? p.xh : p.yh) + (size_t)tt * 65536;
    const u16* __restrict__ Xl = ((scan < 2) ? p.xl : p.yl) + (size_t)tt * 65536;
    const u16* __restrict__ Hch = p.Hh[scan] + (size_t)(t & 1) * 262144;
    const u16* __restrict__ Hcl = p.Hl[scan] + (size_t)(t & 1) * 262144;
    u16* __restrict__ Hnh = p.Hh[scan] + (size_t)((t + 1) & 1) * 262144;
    u16* __restrict__ Hnl = p.Hl[scan] + (size_t)((t + 1) & 1) * 262144;
    float* __restrict__ Cs = p.C[scan];
    const s16x8* __restrict__ wp = (const s16x8*)p.Wp[scan];
    const float* __restrict__ bi = p.ebi[scan];
    const float* __restrict__ bh = p.ebh[scan];
    float* __restrict__ hs = p.hsum[scan];

    const int row0 = rt * 64 + wid * 16;
    const int rowA = row0 + lr;
    const int hc0 = ct * 64;

    f32x4 acc[4][4];
#pragma unroll
    for (int q = 0; q < 4; ++q)
#pragma unroll
        for (int cf = 0; cf < 4; ++cf) {
            int col = q * 256 + hc0 + cf * 16 + lr;
            float bv = bi[col] + bh[col];
            acc[q][cf] = (f32x4){bv, bv, bv, bv};
        }
#pragma unroll 2
    for (int s = 0; s < NS; ++s) {
        int kb = s * 32 + lk8;
        const u16 *ph, *pl2;
        size_t off;
        if (kb < 64) { ph = Xh; pl2 = Xl; off = (size_t)rowA * 64 + kb; }
        else { ph = Hch; pl2 = Hcl; off = (size_t)rowA * 256 + (kb - 64); }
        s16x8 ah = *(const s16x8*)(ph + off), al = *(const s16x8*)(pl2 + off);
#pragma unroll
        for (int q = 0; q < 4; ++q)
#pragma unroll
            for (int cf = 0; cf < 4; ++cf) {
                int fi = s * 64 + q * 16 + ct * 4 + cf;
                s16x8 wh = wp[fi * 128 + l];
                s16x8 wl = wp[fi * 128 + 64 + l];
                mma3(acc[q][cf], ah, al, wh, wl);
            }
    }
#pragma unroll
    for (int cf = 0; cf < 4; ++cf) {
        int hc = hc0 + cf * 16 + lr;
#pragma unroll
        for (int r = 0; r < 4; ++r) {
            int row = row0 + l4 + r;
            size_t co = (size_t)row * 256 + hc;
            float gi = sigf(acc[0][cf][r]);
            float gf = sigf(acc[1][cf][r]);
            float gg = tanh_fast(acc[2][cf][r]);
            float go = sigf(acc[3][cf][r]);
            float cn = gf * Cs[co] + gi * gg;
            float hn = go * tanh_fast(cn);
            Cs[co] = cn;
            split_store(hn, Hnh, Hnl, co);
            hs[(size_t)row * 1024 + hc] += hn;
        }
    }
}

// ---------------- finalize: hsum -> HXY planes ----------------
__global__ __launch_bounds__(256) void finalize_enc(const float* __restrict__ hs,
                                                    u16* __restrict__ Hh,
                                                    u16* __restrict__ Hl) {
    int i = blockIdx.x * 256 + threadIdx.x;  // 1024*1024
    int col = i & 1023;
    float v = hs[i] * ((col < 512) ? (1.f / 64.f) : (1.f / 100.f));
    split_store(v, Hh, Hl, (size_t)i);
}

// ---------------- host ----------------
extern "C" void kernel_launch(void* const* d_in, const int* in_sizes, int n_in,
                              void* d_out, int out_size, void* d_ws, size_t ws_size,
                              hipStream_t stream) {
    (void)in_sizes; (void)n_in; (void)out_size; (void)ws_size;
    auto F = [&](int i) { return (const float*)d_in[i]; };
    const float* x = F(0);
    const float* y = F(1);
    float* out = (float*)d_out;
    char* base = (char*)d_ws;
    const size_t MB = 1ull << 20;
    const size_t KB = 1024;

    // ---- workspace ----
    float* hsumf = (float*)base;                 // 4 MB (encoder phase)
    float* CGF = (float*)base;                   // 8 MB (decoder phase, frag-linear)
    float* encC = (float*)(base + 8 * MB);       // 4 MB
    float* decC = (float*)(base + 12 * MB);      // 2 MB
    char* p = base + 14 * MB;
    u16* encHh = (u16*)p; p += 4 * MB;
    u16* encHl = (u16*)p; p += 4 * MB;
    u16* decHh = (u16*)p; p += 2 * MB;
    u16* decHl = (u16*)p; p += 2 * MB;
    u16* HXYh = (u16*)p; p += 2 * MB;
    u16* HXYl = (u16*)p; p += 2 * MB;
    u16* H1h = (u16*)p; p += 2 * MB;
    u16* H1l = (u16*)p; p += 2 * MB;
    u16* H2h = (u16*)p; p += 1 * MB;
    u16* H2l = (u16*)p; p += 1 * MB;
    u16* muh = (u16*)p; p += 256 * KB;
    u16* mul2 = (u16*)p; p += 256 * KB;
    u16* Ydh = (u16*)p; p += 128 * KB;
    u16* Ydl = (u16*)p; p += 128 * KB;
    u16* Xh = (u16*)p; p += 8 * MB;
    u16* Xl = (u16*)p; p += 8 * MB;
    u16* Yh = (u16*)p; p += (size_t)100 * 1024 * 64 * 2;
    u16* Yl = (u16*)p; p += (size_t)100 * 1024 * 64 * 2;
    u16* W0 = (u16*)p;

    size_t wo = 0;
    auto walloc = [&](size_t elems) { u16* q = W0 + wo; wo += elems * 2; return q; };
    u16* WPX0 = walloc((size_t)1024 * 320);
    u16* WPX1 = walloc((size_t)1024 * 320);
    u16* WPE0 = walloc((size_t)1024 * 320);
    u16* WPE1 = walloc((size_t)1024 * 320);
    u16* WPM1 = walloc((size_t)1024 * 1024);
    u16* WPM2 = walloc((size_t)512 * 1024);
    u16* WPMU = walloc((size_t)128 * 512);
    u16* WPLV = walloc((size_t)128 * 512);
    u16* WPCG = walloc((size_t)2048 * 640);
    u16* WPDG = walloc((size_t)2048 * 576);
    u16* WPD1 = walloc((size_t)1024 * 512);
    u16* WPD2 = walloc((size_t)512 * 1024);
    u16* WPDO = walloc((size_t)64 * 512);

    auto prep = [&](const float* s1, int ld1, int k1, const float* s2, int ld2,
                    u16* o, int N, int KT) {
        prep_w<<<(N * KT / 8) / 256, 256, 0, stream>>>(s1, ld1, k1, s2, ld2, o, N / 16);
    };
    prep(F(2), 64, 64, F(3), 256, WPX0, 1024, 320);
    prep(F(6), 64, 64, F(7), 256, WPX1, 1024, 320);
    prep(F(10), 64, 64, F(11), 256, WPE0, 1024, 320);
    prep(F(14), 64, 64, F(15), 256, WPE1, 1024, 320);
    prep(F(18), 1024, 1024, F(18), 1024, WPM1, 1024, 1024);
    prep(F(20), 1024, 1024, F(20), 1024, WPM2, 512, 1024);
    prep(F(22), 512, 512, F(22), 512, WPMU, 128, 512);
    prep(F(24), 512, 512, F(24), 512, WPLV, 128, 512);
    prep(F(26), 704, 640, F(26), 704, WPCG, 2048, 640);
    prep(F(26) + 640, 704, 64, F(27), 512, WPDG, 2048, 576);
    prep(F(30), 512, 512, F(30), 512, WPD1, 1024, 512);
    prep(F(32), 1024, 1024, F(32), 1024, WPD2, 512, 1024);
    prep(F(34), 512, 512, F(34), 512, WPDO, 64, 512);

    prep_act<<<4096, 256, 0, stream>>>(x, Xh, Xl, 64 * 1024 * 64 / 4);
    prep_act<<<6400, 256, 0, stream>>>(y, Yh, Yl, 100 * 1024 * 64 / 4);

    // zero: hsum(0..4MB) + encC(8..12MB) + decC(12..14MB)
    hipMemsetAsync(base, 0, 14 * MB, stream);

    EncP ep;
    const int wi[4] = {2, 6, 10, 14};
    u16* wps[4] = {WPX0, WPX1, WPE0, WPE1};
    for (int s = 0; s < 4; ++s) {
        ep.Wp[s] = wps[s];
        ep.ebi[s] = F(wi[s] + 2);
        ep.ebh[s] = F(wi[s] + 3);
        ep.Hh[s] = encHh + (size_t)s * 524288;
        ep.Hl[s] = encHl + (size_t)s * 524288;
        ep.C[s] = encC + (size_t)s * 262144;
        ep.hsum[s] = hsumf + (size_t)s * 256;
    }
    ep.xh = Xh; ep.xl = Xl; ep.yh = Yh; ep.yl = Yl;

    // ---- encoder ----
    enc_gates<2><<<256, 256, 0, stream>>>(ep, 0, 0);
    for (int t = 1; t < 64; ++t)
        enc_gates<10><<<256, 256, 0, stream>>>(ep, t, 0);
    for (int t = 64; t < 100; ++t)
        enc_gates<10><<<128, 256, 0, stream>>>(ep, t, 1);

    finalize_enc<<<4096, 256, 0, stream>>>(hsumf, HXYh, HXYl);

    float* muF = out + (size_t)100 * 1024 * 64;
    float* lvF = muF + (size_t)1024 * 128;

    // e_mlp1
    gemm_lds<4, 16, 32, 1, 0, 0, 1><<<256, 256, 0, stream>>>(
        HXYh, HXYl, 1024, 4096, HXYh, HXYl, 1024, WPM1, 64,
        F(19), nullptr, nullptr, 0, nullptr, H1h, H1l, 1024);
    // e_mlp2
    gemm_lds<2, 16, 32, 1, 0, 0, 1><<<256, 256, 0, stream>>>(
        H1h, H1l, 1024, 4096, H1h, H1l, 1024, WPM2, 32,
        F(21), nullptr, nullptr, 0, nullptr, H2h, H2l, 512);
    // heads
    gemm_lds<2, 4, 16, 0, 1, 0, 1><<<64, 256, 0, stream>>>(
        H2h, H2l, 512, 4096, H2h, H2l, 512, WPMU, 8,
        F(23), nullptr, muF, 128, nullptr, muh, mul2, 128);
    gemm_lds<2, 4, 16, 0, 1, 0, 0><<<64, 256, 0, stream>>>(
        H2h, H2l, 512, 4096, H2h, H2l, 512, WPLV, 8,
        F(25), nullptr, lvF, 128, nullptr, nullptr, nullptr, 0);
    // CG -> fragment-linear f32 (overwrites hsum region)
    gemm_lds<8, 16, 20, 0, 0, 1, 0><<<256, 256, 0, stream>>>(
        HXYh, HXYl, 1024, 512, muh, mul2, 128, WPCG, 128,
        F(28), F(29), nullptr, 0, CGF, nullptr, nullptr, 0);

    // ---- decoder ----
    for (int t = 0; t < 100; ++t) {
        const u16* yph = (t == 0) ? (Xh + (size_t)63 * 65536) : Ydh;
        const u16* ypl = (t == 0) ? (Xl + (size_t)63 * 65536) : Ydl;
        const u16* Hch = decHh + (size_t)(t & 1) * 524288;
        const u16* Hcl = decHl + (size_t)(t & 1) * 524288;
        u16* Hnh = decHh + (size_t)((t + 1) & 1) * 524288;
        u16* Hnl = decHl + (size_t)((t + 1) & 1) * 524288;
        if (t == 0)
            dec_gates_lds<2><<<256, 256, 0, stream>>>(yph, ypl, Hch, Hcl, WPDG, CGF,
                                                      Hnh, Hnl, decC);
        else
            dec_gates_lds<18><<<256, 256, 0, stream>>>(yph, ypl, Hch, Hcl, WPDG, CGF,
                                                       Hnh, Hnl, decC);
        // d_mlp1
        gemm_lds<4, 16, 16, 1, 0, 0, 1><<<256, 256, 0, stream>>>(
            Hnh, Hnl, 512, 4096, Hnh, Hnl, 512, WPD1, 64,
            F(31), nullptr, nullptr, 0, nullptr, H1h, H1l, 1024);
        // d_mlp2
        gemm_lds<2, 16, 32, 1, 0, 0, 1><<<256, 256, 0, stream>>>(
            H1h, H1l, 1024, 4096, H1h, H1l, 1024, WPD2, 32,
            F(33), nullptr, nullptr, 0, nullptr, H2h, H2l, 512);
        // d_out
        gemm_lds<4, 1, 16, 0, 1, 0, 1><<<16, 256, 0, stream>>>(
            H2h, H2l, 512, 4096, H2h, H2l, 512, WPDO, 4,
            F(35), nullptr, out + (size_t)t * 65536, 64, nullptr, Ydh, Ydl, 64);
    }
}

// Round 10
// 9729.936 us; speedup vs baseline: 8.9750x; 1.0116x over previous
//
#include <hip/hip_runtime.h>

typedef unsigned short u16;
typedef unsigned int u32;
typedef __attribute__((ext_vector_type(8))) short s16x8;
typedef __attribute__((ext_vector_type(4))) float f32x4;

#define MFMA_BF16 __builtin_amdgcn_mfma_f32_16x16x32_bf16
#define SCOPE_AGT __HIP_MEMORY_SCOPE_AGENT

__device__ __forceinline__ float sigf(float x) { return 1.f / (1.f + __expf(-x)); }
__device__ __forceinline__ float tanh_fast(float x) {
    float e = __expf(2.f * x);
    return 1.f - 2.f / (e + 1.f);
}
__device__ __forceinline__ u16 bf16_rn(float x) {
    u32 u = __float_as_uint(x);
    u += 0x7FFFu + ((u >> 16) & 1u);
    return (u16)(u >> 16);
}
__device__ __forceinline__ void split_store(float v, u16* __restrict__ ph,
                                            u16* __restrict__ pl, size_t off) {
    u16 h = bf16_rn(v);
    float hf = __uint_as_float(((u32)h) << 16);
    ph[off] = h;
    pl[off] = bf16_rn(v - hf);
}
__device__ __forceinline__ void mma3(f32x4& acc, s16x8 ah, s16x8 al, s16x8 wh, s16x8 wl) {
    acc = MFMA_BF16(ah, wh, acc, 0, 0, 0);
    acc = MFMA_BF16(al, wh, acc, 0, 0, 0);
    acc = MFMA_BF16(ah, wl, acc, 0, 0, 0);
}
__device__ __forceinline__ void gll16(const u16* g, u16* l) {
    __builtin_amdgcn_global_load_lds(
        (const __attribute__((address_space(1))) u32*)g,
        (__attribute__((address_space(3))) u32*)l, 16, 0, 0);
}

// ---------------- weight prep: fragment blocks, plane-separated ----------------
// frag-block u = s*NF+f: u16[1024]: hi[64 lanes][8] at +0, lo at +512.
__global__ __launch_bounds__(256) void prep_w(const float* __restrict__ S1, int ld1, int K1,
                                              const float* __restrict__ S2, int ld2,
                                              u16* __restrict__ out, int NF) {
    int idx = blockIdx.x * 256 + threadIdx.x;
    int l = idx & 63;
    int u = idx >> 6;
    int f = u % NF;
    int s = u / NF;
    int n = f * 16 + (l & 15);
    int kb = s * 32 + ((l >> 4) << 3);
    u16* o = out + (size_t)u * 1024 + l * 8;
#pragma unroll
    for (int j = 0; j < 8; ++j) {
        int k = kb + j;
        float v = (k < K1) ? S1[(size_t)n * ld1 + k] : S2[(size_t)n * ld2 + (k - K1)];
        u16 h = bf16_rn(v);
        float hf = __uint_as_float(((u32)h) << 16);
        o[j] = h;
        o[512 + j] = bf16_rn(v - hf);
    }
}

__global__ __launch_bounds__(256) void prep_act(const float* __restrict__ in,
                                                u16* __restrict__ hi, u16* __restrict__ lo,
                                                int n4) {
    int i = blockIdx.x * 256 + threadIdx.x;
    if (i >= n4) return;
    float4 v = ((const float4*)in)[i];
    float vv[4] = {v.x, v.y, v.z, v.w};
    u16 h[4], lw[4];
#pragma unroll
    for (int j = 0; j < 4; ++j) {
        h[j] = bf16_rn(vv[j]);
        float hf = __uint_as_float(((u32)h[j]) << 16);
        lw[j] = bf16_rn(vv[j] - hf);
    }
    ((ushort4*)hi)[i] = make_ushort4(h[0], h[1], h[2], h[3]);
    ((ushort4*)lo)[i] = make_ushort4(lw[0], lw[1], lw[2], lw[3]);
}

// ---------------- barriers ----------------
// XCD-local: relaxed flag store + relaxed poll + L1-only invalidate. No L2 flush.
// Group = {b : b&7 == xcd} (32 blocks) — same pattern validated in R6.
__device__ __forceinline__ void barx(u32* __restrict__ flags, int xcd, u32 k) {
    __syncthreads();
    if (threadIdx.x == 0)
        __hip_atomic_store(&flags[blockIdx.x * 16], k, __ATOMIC_RELAXED, SCOPE_AGT);
    if (threadIdx.x < 64) {
        int i = threadIdx.x & 31;
        const u32* fp = &flags[(xcd + i * 8) * 16];
        for (;;) {
            u32 v = __hip_atomic_load(fp, __ATOMIC_RELAXED, SCOPE_AGT);
            if (__all((int)(v >= k))) break;
            __builtin_amdgcn_s_sleep(2);
        }
    }
    if (threadIdx.x == 0) asm volatile("buffer_inv" ::: "memory");
    __syncthreads();
}

// Device-wide: full agent fences. Used exactly once.
__device__ __forceinline__ void barg(u32* __restrict__ flags, u32 k) {
    __syncthreads();
    if (threadIdx.x == 0) {
        __builtin_amdgcn_fence(__ATOMIC_RELEASE, "agent");
        __hip_atomic_store(&flags[blockIdx.x * 16], k, __ATOMIC_RELAXED, SCOPE_AGT);
    }
    if (threadIdx.x < 64) {
        for (;;) {
            u32 mn = 0xFFFFFFFFu;
#pragma unroll
            for (int j = 0; j < 4; ++j) {
                u32 v = __hip_atomic_load(&flags[((int)threadIdx.x * 4 + j) * 16],
                                          __ATOMIC_RELAXED, SCOPE_AGT);
                mn = v < mn ? v : mn;
            }
            if (__all((int)(mn >= k))) break;
            __builtin_amdgcn_s_sleep(8);
        }
    }
    if (threadIdx.x == 0) __builtin_amdgcn_fence(__ATOMIC_ACQUIRE, "agent");
    __syncthreads();
}

// ---------------- params ----------------
struct AllP {
    const u16 *Xh, *Xl, *Yh, *Yl;
    const float* ebi[4];
    const float* ebh[4];
    const float *b19, *b21, *b23, *b25, *b28, *b29, *b31, *b33, *b35;
    const u16* Wenc[4];
    const u16 *Wm1, *Wm2, *Wmu, *Wlv, *Wcg, *Wdg, *Wd1, *Wd2, *Wdo;
    u16 *encHh, *encHl, *decHh, *decHl;
    u16 *HXYh, *HXYl, *H1h, *H1l, *H2h, *H2l, *muh, *mul2, *Ydh, *Ydl;
    float* CGF;
    float *outY, *muF, *lvF;
    u32 *gflags, *xflags;
};

// ---------------- staged GEMM phase (R9 inner loop as device fn) ----------------
template <int CF>
__device__ __forceinline__ void pstage_gemm(
    u16* sm, int ns, int row0, int fbase,
    const u16* __restrict__ A1h, const u16* __restrict__ A1l, int ld1, int K1,
    const u16* __restrict__ A2h, const u16* __restrict__ A2l, int ld2,
    const u16* __restrict__ Wp, int NF,
    const float* __restrict__ b1, const float* __restrict__ b2, int ACT,
    float* __restrict__ outFrag, int fragbase,
    u16* __restrict__ Oh, u16* __restrict__ Ol, int ldop,
    int wid, int l, int lr, int lk8, int l4) {
    const int rowA = row0 + lr;
    auto stage = [&](int s, int buf) {
        const u16* wsrc = Wp + (size_t)(s * NF + fbase) * 1024;
#pragma unroll
        for (int i = 0; i < CF / 2; ++i)
            gll16(wsrc + i * 2048 + wid * 512 + l * 8,
                  sm + buf * CF * 1024 + i * 2048 + wid * 512);
    };
    f32x4 acc[CF] = {};
    stage(0, 0);
    __syncthreads();
    for (int s = 0; s < ns; ++s) {
        if (s + 1 < ns) stage(s + 1, (s + 1) & 1);
        int kb = s * 32 + lk8;
        const u16 *ph, *pl2;
        size_t off;
        if (kb < K1) { ph = A1h; pl2 = A1l; off = (size_t)rowA * ld1 + kb; }
        else { ph = A2h; pl2 = A2l; off = (size_t)rowA * ld2 + (kb - K1); }
        s16x8 ah = *(const s16x8*)(ph + off), al = *(const s16x8*)(pl2 + off);
        const u16* cur = sm + (s & 1) * CF * 1024;
#pragma unroll
        for (int cf = 0; cf < CF; ++cf) {
            s16x8 wh = *(const s16x8*)(cur + cf * 1024 + l * 8);
            s16x8 wl = *(const s16x8*)(cur + cf * 1024 + 512 + l * 8);
            mma3(acc[cf], ah, al, wh, wl);
        }
        __syncthreads();
    }
#pragma unroll
    for (int cf = 0; cf < CF; ++cf) {
        int col = (fbase + cf) * 16 + lr;
        float bv = (b1 ? b1[col] : 0.f) + (b2 ? b2[col] : 0.f);
        f32x4 v4;
#pragma unroll
        for (int r = 0; r < 4; ++r) {
            float v = acc[cf][r] + bv;
            if (ACT) v = tanh_fast(v);
            v4[r] = v;
            int row = row0 + l4 + r;
            if (Oh) split_store(v, Oh, Ol, (size_t)row * ldop + col);
        }
        if (outFrag) *(f32x4*)(outFrag + (size_t)(fragbase + cf) * 256 + l * 4) = v4;
    }
}

// ---------------- direct-load GEMM (small weights) ----------------
template <int CF>
__device__ __forceinline__ void pdirect_gemm(
    int ns, int row0, int fbase,
    const u16* __restrict__ A1h, const u16* __restrict__ A1l, int ld1,
    const u16* __restrict__ Wp, int NF,
    const float* __restrict__ b1, int ACT,
    float* __restrict__ outF, int ldo,
    u16* __restrict__ Oh, u16* __restrict__ Ol, int ldop,
    int l, int lr, int lk8, int l4) {
    const s16x8* wp = (const s16x8*)Wp;
    const int rowA = row0 + lr;
    f32x4 acc[CF] = {};
    for (int s = 0; s < ns; ++s) {
        int kb = s * 32 + lk8;
        size_t off = (size_t)rowA * ld1 + kb;
        s16x8 ah = *(const s16x8*)(A1h + off), al = *(const s16x8*)(A1l + off);
#pragma unroll
        for (int cf = 0; cf < CF; ++cf) {
            int fi = s * NF + fbase + cf;
            mma3(acc[cf], ah, al, wp[fi * 128 + l], wp[fi * 128 + 64 + l]);
        }
    }
#pragma unroll
    for (int cf = 0; cf < CF; ++cf) {
        int col = (fbase + cf) * 16 + lr;
        float bv = b1 ? b1[col] : 0.f;
#pragma unroll
        for (int r = 0; r < 4; ++r) {
            float v = acc[cf][r] + bv;
            if (ACT) v = tanh_fast(v);
            int row = row0 + l4 + r;
            if (outF) outF[(size_t)row * ldo + col] = v;
            if (Oh) split_store(v, Oh, Ol, (size_t)row * ldop + col);
        }
    }
}

// ---------------- the persistent kernel ----------------
__global__ __launch_bounds__(256) void vae_persist(AllP P) {
    __shared__ u16 sm[16384];  // 32 KB, double-buffered staging
    const int tid = threadIdx.x, b = blockIdx.x;
    const int wid = tid >> 6, l = tid & 63;
    const int lr = l & 15, lk8 = (l >> 4) * 8, l4 = (l >> 4) * 4;
    const int xcd = b & 7, bm = b >> 3;  // 32 blocks per XCD group
    u32 xk = 0;

    // ================= encoder: XCD-local (scan = xcd>>1, row half = xcd&1) =============
    {
        const int scan = xcd >> 1;
        const int rowbase = (xcd & 1) * 512;
        const int T = (scan < 2) ? 64 : 100;
        const int rev = scan & 1;
        const u16* Xb = (scan < 2) ? P.Xh : P.Yh;
        const u16* Xlb = (scan < 2) ? P.Xl : P.Yl;
        const s16x8* wp = (const s16x8*)P.Wenc[scan];
        const float* bi = P.ebi[scan];
        const float* bh = P.ebh[scan];
        u16* Hhb = P.encHh + (size_t)scan * 524288;
        u16* Hlb = P.encHl + (size_t)scan * 524288;
        const int rt = bm >> 2, ct = bm & 3;
        const int row0 = rowbase + rt * 64 + wid * 16;
        const int rowA = row0 + lr;
        const int hc0 = ct * 64;
        float cst[4][4] = {};
        float hsr[4][4] = {};

        for (int t = 0; t < T; ++t) {
            const int tt = rev ? (T - 1 - t) : t;
            const u16* xh = Xb + (size_t)tt * 65536;
            const u16* xl = Xlb + (size_t)tt * 65536;
            const u16* Hch = Hhb + (size_t)(t & 1) * 262144;
            const u16* Hcl = Hlb + (size_t)(t & 1) * 262144;
            u16* Hnh = Hhb + (size_t)((t + 1) & 1) * 262144;
            u16* Hnl = Hlb + (size_t)((t + 1) & 1) * 262144;
            f32x4 acc[4][4];
#pragma unroll
            for (int q = 0; q < 4; ++q)
#pragma unroll
                for (int cf = 0; cf < 4; ++cf) {
                    int col = q * 256 + hc0 + cf * 16 + lr;
                    float bv = bi[col] + bh[col];
                    acc[q][cf] = (f32x4){bv, bv, bv, bv};
                }
            const int NS = (t == 0) ? 2 : 10;
            for (int s = 0; s < NS; ++s) {
                int kb = s * 32 + lk8;
                const u16 *ph, *pl2;
                size_t off;
                if (kb < 64) { ph = xh; pl2 = xl; off = (size_t)rowA * 64 + kb; }
                else { ph = Hch; pl2 = Hcl; off = (size_t)rowA * 256 + (kb - 64); }
                s16x8 ah = *(const s16x8*)(ph + off), al = *(const s16x8*)(pl2 + off);
#pragma unroll
                for (int q = 0; q < 4; ++q)
#pragma unroll
                    for (int cf = 0; cf < 4; ++cf) {
                        int fi = s * 64 + q * 16 + ct * 4 + cf;
                        mma3(acc[q][cf], ah, al, wp[fi * 128 + l], wp[fi * 128 + 64 + l]);
                    }
            }
#pragma unroll
            for (int cf = 0; cf < 4; ++cf) {
                int hc = hc0 + cf * 16 + lr;
#pragma unroll
                for (int r = 0; r < 4; ++r) {
                    int row = row0 + l4 + r;
                    size_t co = (size_t)row * 256 + hc;
                    float gi = sigf(acc[0][cf][r]);
                    float gf = sigf(acc[1][cf][r]);
                    float gg = tanh_fast(acc[2][cf][r]);
                    float go = sigf(acc[3][cf][r]);
                    float cn = gf * cst[cf][r] + gi * gg;
                    float hn = go * tanh_fast(cn);
                    cst[cf][r] = cn;
                    hsr[cf][r] += hn;
                    split_store(hn, Hnh, Hnl, co);
                }
            }
            barx(P.xflags, xcd, ++xk);
        }
        float sc = (scan < 2) ? (1.f / 64.f) : (1.f / 100.f);
#pragma unroll
        for (int cf = 0; cf < 4; ++cf) {
            int col = scan * 256 + hc0 + cf * 16 + lr;
#pragma unroll
            for (int r = 0; r < 4; ++r) {
                int row = row0 + l4 + r;
                split_store(hsr[cf][r] * sc, P.HXYh, P.HXYl, (size_t)row * 1024 + col);
            }
        }
    }
    barg(P.gflags, 1);  // the ONLY cross-XCD handoff

    // ================= middle (rows xcd*128..+127, all XCD-local) =================
    {
        const int rt = bm & 1, ct = bm >> 1;
        pstage_gemm<4>(sm, 32, xcd * 128 + rt * 64 + wid * 16, ct * 4,
                       P.HXYh, P.HXYl, 1024, 4096, nullptr, nullptr, 0,
                       P.Wm1, 64, P.b19, nullptr, 1,
                       nullptr, 0, P.H1h, P.H1l, 1024, wid, l, lr, lk8, l4);
    }
    barx(P.xflags, xcd, ++xk);
    {
        const int rt = bm & 1, ct = bm >> 1;
        pstage_gemm<2>(sm, 32, xcd * 128 + rt * 64 + wid * 16, ct * 2,
                       P.H1h, P.H1l, 1024, 4096, nullptr, nullptr, 0,
                       P.Wm2, 32, P.b21, nullptr, 1,
                       nullptr, 0, P.H2h, P.H2l, 512, wid, l, lr, lk8, l4);
    }
    barx(P.xflags, xcd, ++xk);
    {
        const int rt = bm & 1, cfi = (bm >> 1) & 7;
        if (bm < 16)
            pdirect_gemm<1>(16, xcd * 128 + rt * 64 + wid * 16, cfi,
                            P.H2h, P.H2l, 512, P.Wmu, 8, P.b23, 0,
                            P.muF, 128, P.muh, P.mul2, 128, l, lr, lk8, l4);
        else
            pdirect_gemm<1>(16, xcd * 128 + rt * 64 + wid * 16, cfi,
                            P.H2h, P.H2l, 512, P.Wlv, 8, P.b25, 0,
                            P.lvF, 128, nullptr, nullptr, 0, l, lr, lk8, l4);
    }
    barx(P.xflags, xcd, ++xk);
    {
        const int rt = bm & 1, ct = bm >> 1;
        const int fragbase = (xcd * 8 + rt * 4 + wid) * 128 + ct * 8;
        pstage_gemm<8>(sm, 20, xcd * 128 + rt * 64 + wid * 16, ct * 8,
                       P.HXYh, P.HXYl, 1024, 512, P.muh, P.mul2, 128,
                       P.Wcg, 128, P.b28, P.b29, 0,
                       P.CGF, fragbase, nullptr, nullptr, 0, wid, l, lr, lk8, l4);
    }
    barx(P.xflags, xcd, ++xk);

    // ================= decoder (rows xcd*128..+127, all XCD-local) =================
    float cds[2][4] = {};
    for (int t = 0; t < 100; ++t) {
        // ---- gates + cell ----
        {
            const int rt = bm >> 4, ct = bm & 15;
            const int row0 = xcd * 128 + rt * 64 + wid * 16;
            const int rowA = row0 + lr;
            const int RT = xcd * 8 + rt * 4 + wid;
            const u16* yph = (t == 0) ? (P.Xh + (size_t)63 * 65536) : P.Ydh;
            const u16* ypl = (t == 0) ? (P.Xl + (size_t)63 * 65536) : P.Ydl;
            const u16* Hch = P.decHh + (size_t)(t & 1) * 524288;
            const u16* Hcl = P.decHl + (size_t)(t & 1) * 524288;
            u16* Hnh = P.decHh + (size_t)((t + 1) & 1) * 524288;
            u16* Hnl = P.decHl + (size_t)((t + 1) & 1) * 524288;
            auto stg = [&](int s, int buf) {
#pragma unroll
                for (int q = 0; q < 4; ++q)
                    gll16(P.Wdg + (size_t)(s * 128 + q * 32 + ct * 2) * 1024 + wid * 512 + l * 8,
                          sm + buf * 8192 + q * 2048 + wid * 512);
            };
            f32x4 acc[4][2];
#pragma unroll
            for (int q = 0; q < 4; ++q)
#pragma unroll
                for (int cf = 0; cf < 2; ++cf)
                    acc[q][cf] = *(const f32x4*)(P.CGF +
                                 (size_t)(RT * 128 + q * 32 + ct * 2 + cf) * 256 + l * 4);
            const int ns = (t == 0) ? 2 : 18;
            stg(0, 0);
            __syncthreads();
            for (int s = 0; s < ns; ++s) {
                if (s + 1 < ns) stg(s + 1, (s + 1) & 1);
                int kb = s * 32 + lk8;
                const u16 *ph, *pl2;
                size_t off;
                if (kb < 64) { ph = yph; pl2 = ypl; off = (size_t)rowA * 64 + kb; }
                else { ph = Hch; pl2 = Hcl; off = (size_t)rowA * 512 + (kb - 64); }
                s16x8 ah = *(const s16x8*)(ph + off), al = *(const s16x8*)(pl2 + off);
                const u16* cur = sm + (s & 1) * 8192;
#pragma unroll
                for (int q = 0; q < 4; ++q)
#pragma unroll
                    for (int cf = 0; cf < 2; ++cf) {
                        s16x8 wh = *(const s16x8*)(cur + q * 2048 + cf * 1024 + l * 8);
                        s16x8 wl = *(const s16x8*)(cur + q * 2048 + cf * 1024 + 512 + l * 8);
                        mma3(acc[q][cf], ah, al, wh, wl);
                    }
                __syncthreads();
            }
            const int hc0 = ct * 32;
#pragma unroll
            for (int cf = 0; cf < 2; ++cf) {
                int hc = hc0 + cf * 16 + lr;
#pragma unroll
                for (int r = 0; r < 4; ++r) {
                    int row = row0 + l4 + r;
                    size_t co = (size_t)row * 512 + hc;
                    float gi = sigf(acc[0][cf][r]);
                    float gf = sigf(acc[1][cf][r]);
                    float gg = tanh_fast(acc[2][cf][r]);
                    float go = sigf(acc[3][cf][r]);
                    float cold = (t == 0) ? 0.f : cds[cf][r];
                    float cn = gf * cold + gi * gg;
                    float hn = go * tanh_fast(cn);
                    cds[cf][r] = cn;
                    split_store(hn, Hnh, Hnl, co);
                }
            }
        }
        barx(P.xflags, xcd, ++xk);
        {
            const u16* Hnh = P.decHh + (size_t)((t + 1) & 1) * 524288;
            const u16* Hnl = P.decHl + (size_t)((t + 1) & 1) * 524288;
            const int rt = bm & 1, ct = bm >> 1;
            pstage_gemm<4>(sm, 16, xcd * 128 + rt * 64 + wid * 16, ct * 4,
                           Hnh, Hnl, 512, 4096, nullptr, nullptr, 0,
                           P.Wd1, 64, P.b31, nullptr, 1,
                           nullptr, 0, P.H1h, P.H1l, 1024, wid, l, lr, lk8, l4);
        }
        barx(P.xflags, xcd, ++xk);
        {
            const int rt = bm & 1, ct = bm >> 1;
            pstage_gemm<2>(sm, 32, xcd * 128 + rt * 64 + wid * 16, ct * 2,
                           P.H1h, P.H1l, 1024, 4096, nullptr, nullptr, 0,
                           P.Wd2, 32, P.b33, nullptr, 1,
                           nullptr, 0, P.H2h, P.H2l, 512, wid, l, lr, lk8, l4);
        }
        barx(P.xflags, xcd, ++xk);
        if (bm < 2)
            pdirect_gemm<4>(16, xcd * 128 + bm * 64 + wid * 16, 0,
                            P.H2h, P.H2l, 512, P.Wdo, 4, P.b35, 0,
                            P.outY + (size_t)t * 65536, 64,
                            P.Ydh, P.Ydl, 64, l, lr, lk8, l4);
        barx(P.xflags, xcd, ++xk);
    }
}

// ---------------- host ----------------
extern "C" void kernel_launch(void* const* d_in, const int* in_sizes, int n_in,
                              void* d_out, int out_size, void* d_ws, size_t ws_size,
                              hipStream_t stream) {
    (void)in_sizes; (void)n_in; (void)out_size; (void)ws_size;
    auto F = [&](int i) { return (const float*)d_in[i]; };
    const float* x = F(0);
    const float* y = F(1);
    float* out = (float*)d_out;
    char* base = (char*)d_ws;
    const size_t MB = 1ull << 20;
    const size_t KB = 1024;

    AllP P;
    P.gflags = (u32*)base;                       // 16 KB
    P.xflags = (u32*)(base + 16 * KB);           // 16 KB
    char* p = base + 64 * KB;
    P.CGF = (float*)p; p += 8 * MB;              // 64 rowtiles x 128 frags x 256 f32
    P.encHh = (u16*)p; p += 4 * MB;
    P.encHl = (u16*)p; p += 4 * MB;
    P.decHh = (u16*)p; p += 2 * MB;
    P.decHl = (u16*)p; p += 2 * MB;
    P.HXYh = (u16*)p; p += 2 * MB;
    P.HXYl = (u16*)p; p += 2 * MB;
    P.H1h = (u16*)p; p += 2 * MB;
    P.H1l = (u16*)p; p += 2 * MB;
    P.H2h = (u16*)p; p += 1 * MB;
    P.H2l = (u16*)p; p += 1 * MB;
    P.muh = (u16*)p; p += 256 * KB;
    P.mul2 = (u16*)p; p += 256 * KB;
    P.Ydh = (u16*)p; p += 128 * KB;
    P.Ydl = (u16*)p; p += 128 * KB;
    u16* Xh = (u16*)p; p += 8 * MB;
    u16* Xl = (u16*)p; p += 8 * MB;
    u16* Yh = (u16*)p; p += (size_t)100 * 1024 * 64 * 2;
    u16* Yl = (u16*)p; p += (size_t)100 * 1024 * 64 * 2;
    u16* W0 = (u16*)p;

    size_t wo = 0;
    auto walloc = [&](size_t elems) { u16* q = W0 + wo; wo += elems * 2; return q; };
    u16* WPX0 = walloc((size_t)1024 * 320);
    u16* WPX1 = walloc((size_t)1024 * 320);
    u16* WPE0 = walloc((size_t)1024 * 320);
    u16* WPE1 = walloc((size_t)1024 * 320);
    u16* WPM1 = walloc((size_t)1024 * 1024);
    u16* WPM2 = walloc((size_t)512 * 1024);
    u16* WPMU = walloc((size_t)128 * 512);
    u16* WPLV = walloc((size_t)128 * 512);
    u16* WPCG = walloc((size_t)2048 * 640);
    u16* WPDG = walloc((size_t)2048 * 576);
    u16* WPD1 = walloc((size_t)1024 * 512);
    u16* WPD2 = walloc((size_t)512 * 1024);
    u16* WPDO = walloc((size_t)64 * 512);

    auto prep = [&](const float* s1, int ld1, int k1, const float* s2, int ld2,
                    u16* o, int N, int KT) {
        prep_w<<<(N * KT / 8) / 256, 256, 0, stream>>>(s1, ld1, k1, s2, ld2, o, N / 16);
    };
    prep(F(2), 64, 64, F(3), 256, WPX0, 1024, 320);
    prep(F(6), 64, 64, F(7), 256, WPX1, 1024, 320);
    prep(F(10), 64, 64, F(11), 256, WPE0, 1024, 320);
    prep(F(14), 64, 64, F(15), 256, WPE1, 1024, 320);
    prep(F(18), 1024, 1024, F(18), 1024, WPM1, 1024, 1024);
    prep(F(20), 1024, 1024, F(20), 1024, WPM2, 512, 1024);
    prep(F(22), 512, 512, F(22), 512, WPMU, 128, 512);
    prep(F(24), 512, 512, F(24), 512, WPLV, 128, 512);
    prep(F(26), 704, 640, F(26), 704, WPCG, 2048, 640);
    prep(F(26) + 640, 704, 64, F(27), 512, WPDG, 2048, 576);
    prep(F(30), 512, 512, F(30), 512, WPD1, 1024, 512);
    prep(F(32), 1024, 1024, F(32), 1024, WPD2, 512, 1024);
    prep(F(34), 512, 512, F(34), 512, WPDO, 64, 512);

    prep_act<<<4096, 256, 0, stream>>>(x, Xh, Xl, 64 * 1024 * 64 / 4);
    prep_act<<<6400, 256, 0, stream>>>(y, Yh, Yl, 100 * 1024 * 64 / 4);

    hipMemsetAsync(base, 0, 64 * KB, stream);  // barrier flags only (states live in VGPRs)

    P.Xh = Xh; P.Xl = Xl; P.Yh = Yh; P.Yl = Yl;
    const int wi[4] = {2, 6, 10, 14};
    u16* wps[4] = {WPX0, WPX1, WPE0, WPE1};
    for (int s = 0; s < 4; ++s) {
        P.Wenc[s] = wps[s];
        P.ebi[s] = F(wi[s] + 2);
        P.ebh[s] = F(wi[s] + 3);
    }
    P.Wm1 = WPM1; P.Wm2 = WPM2; P.Wmu = WPMU; P.Wlv = WPLV;
    P.Wcg = WPCG; P.Wdg = WPDG; P.Wd1 = WPD1; P.Wd2 = WPD2; P.Wdo = WPDO;
    P.b19 = F(19); P.b21 = F(21); P.b23 = F(23); P.b25 = F(25);
    P.b28 = F(28); P.b29 = F(29); P.b31 = F(31); P.b33 = F(33); P.b35 = F(35);
    P.outY = out;
    P.muF = out + (size_t)100 * 1024 * 64;
    P.lvF = P.muF + (size_t)1024 * 128;

    vae_persist<<<256, 256, 0, stream>>>(P);
}

// Round 11
// 8762.530 us; speedup vs baseline: 9.9658x; 1.1104x over previous
//
#include <hip/hip_runtime.h>

typedef unsigned short u16;
typedef unsigned int u32;
typedef __attribute__((ext_vector_type(8))) short s16x8;
typedef __attribute__((ext_vector_type(4))) float f32x4;

#define MFMA_BF16 __builtin_amdgcn_mfma_f32_16x16x32_bf16
#define SCOPE_AGT __HIP_MEMORY_SCOPE_AGENT

__device__ __forceinline__ float sigf(float x) { return 1.f / (1.f + __expf(-x)); }
__device__ __forceinline__ float tanh_fast(float x) {
    float e = __expf(2.f * x);
    return 1.f - 2.f / (e + 1.f);
}
__device__ __forceinline__ u16 bf16_rn(float x) {
    u32 u = __float_as_uint(x);
    u += 0x7FFFu + ((u >> 16) & 1u);
    return (u16)(u >> 16);
}
__device__ __forceinline__ void split_store(float v, u16* __restrict__ ph,
                                            u16* __restrict__ pl, size_t off) {
    u16 h = bf16_rn(v);
    float hf = __uint_as_float(((u32)h) << 16);
    ph[off] = h;
    pl[off] = bf16_rn(v - hf);
}
__device__ __forceinline__ void mma3(f32x4& acc, s16x8 ah, s16x8 al, s16x8 wh, s16x8 wl) {
    acc = MFMA_BF16(ah, wh, acc, 0, 0, 0);
    acc = MFMA_BF16(al, wh, acc, 0, 0, 0);
    acc = MFMA_BF16(ah, wl, acc, 0, 0, 0);
}
__device__ __forceinline__ void gll16(const u16* g, u16* l) {
    __builtin_amdgcn_global_load_lds(
        (const __attribute__((address_space(1))) u32*)g,
        (__attribute__((address_space(3))) u32*)l, 16, 0, 0);
}

// ---------------- weight prep: fragment blocks, plane-separated ----------------
__global__ __launch_bounds__(256) void prep_w(const float* __restrict__ S1, int ld1, int K1,
                                              const float* __restrict__ S2, int ld2,
                                              u16* __restrict__ out, int NF) {
    int idx = blockIdx.x * 256 + threadIdx.x;
    int l = idx & 63;
    int u = idx >> 6;
    int f = u % NF;
    int s = u / NF;
    int n = f * 16 + (l & 15);
    int kb = s * 32 + ((l >> 4) << 3);
    u16* o = out + (size_t)u * 1024 + l * 8;
#pragma unroll
    for (int j = 0; j < 8; ++j) {
        int k = kb + j;
        float v = (k < K1) ? S1[(size_t)n * ld1 + k] : S2[(size_t)n * ld2 + (k - K1)];
        u16 h = bf16_rn(v);
        float hf = __uint_as_float(((u32)h) << 16);
        o[j] = h;
        o[512 + j] = bf16_rn(v - hf);
    }
}

__global__ __launch_bounds__(256) void prep_act(const float* __restrict__ in,
                                                u16* __restrict__ hi, u16* __restrict__ lo,
                                                int n4) {
    int i = blockIdx.x * 256 + threadIdx.x;
    if (i >= n4) return;
    float4 v = ((const float4*)in)[i];
    float vv[4] = {v.x, v.y, v.z, v.w};
    u16 h[4], lw[4];
#pragma unroll
    for (int j = 0; j < 4; ++j) {
        h[j] = bf16_rn(vv[j]);
        float hf = __uint_as_float(((u32)h[j]) << 16);
        lw[j] = bf16_rn(vv[j] - hf);
    }
    ((ushort4*)hi)[i] = make_ushort4(h[0], h[1], h[2], h[3]);
    ((ushort4*)lo)[i] = make_ushort4(lw[0], lw[1], lw[2], lw[3]);
}

// ---------------- barriers ----------------
// XCD-local (group = 64 blocks with b&7==xcd): relaxed flags + L1-only invalidate.
__device__ __forceinline__ void barx(u32* __restrict__ flags, int xcd, u32 k) {
    __syncthreads();
    if (threadIdx.x == 0)
        __hip_atomic_store(&flags[blockIdx.x * 16], k, __ATOMIC_RELAXED, SCOPE_AGT);
    if (threadIdx.x < 64) {
        const u32* fp = &flags[(xcd + (int)threadIdx.x * 8) * 16];
        for (;;) {
            u32 v = __hip_atomic_load(fp, __ATOMIC_RELAXED, SCOPE_AGT);
            if (__all((int)(v >= k))) break;
            __builtin_amdgcn_s_sleep(2);
        }
    }
    if (threadIdx.x == 0) asm volatile("buffer_inv" ::: "memory");
    __syncthreads();
}

// Device-wide: full agent fences. Used exactly once (512 blocks).
__device__ __forceinline__ void barg(u32* __restrict__ flags, u32 k) {
    __syncthreads();
    if (threadIdx.x == 0) {
        __builtin_amdgcn_fence(__ATOMIC_RELEASE, "agent");
        __hip_atomic_store(&flags[blockIdx.x * 16], k, __ATOMIC_RELAXED, SCOPE_AGT);
    }
    if (threadIdx.x < 64) {
        for (;;) {
            u32 mn = 0xFFFFFFFFu;
#pragma unroll
            for (int j = 0; j < 8; ++j) {
                u32 v = __hip_atomic_load(&flags[((int)threadIdx.x * 8 + j) * 16],
                                          __ATOMIC_RELAXED, SCOPE_AGT);
                mn = v < mn ? v : mn;
            }
            if (__all((int)(mn >= k))) break;
            __builtin_amdgcn_s_sleep(8);
        }
    }
    if (threadIdx.x == 0) __builtin_amdgcn_fence(__ATOMIC_ACQUIRE, "agent");
    __syncthreads();
}

// ---------------- params ----------------
struct AllP {
    const u16 *Xh, *Xl, *Yh, *Yl;
    const float* ebi[4];
    const float* ebh[4];
    const float *b19, *b21, *b23, *b25, *b28, *b29, *b31, *b33, *b35;
    const u16* Wenc[4];
    const u16 *Wm1, *Wm2, *Wmu, *Wlv, *Wcg, *Wdg, *Wd1, *Wd2, *Wdo;
    u16 *encHh, *encHl, *decHh, *decHl;
    u16 *HXYh, *HXYl, *H1h, *H1l, *H2h, *H2l, *muh, *mul2, *Ydh, *Ydl;
    float* CGF;
    float *outY, *muF, *lvF;
    u32 *gflags, *xflags;
};

// ---------------- staged GEMM phase (chunked staging, any CF) ----------------
template <int CF>
__device__ __forceinline__ void pstage_gemm(
    u16* sm, int ns, int row0, int fbase,
    const u16* __restrict__ A1h, const u16* __restrict__ A1l, int ld1, int K1,
    const u16* __restrict__ A2h, const u16* __restrict__ A2l, int ld2,
    const u16* __restrict__ Wp, int NF,
    const float* __restrict__ b1, const float* __restrict__ b2, int ACT,
    float* __restrict__ outFrag, int fragbase,
    u16* __restrict__ Oh, u16* __restrict__ Ol, int ldop,
    int wid, int l, int lr, int lk8, int l4) {
    const int rowA = row0 + lr;
    auto stage = [&](int s, int buf) {
        const u16* wsrc = Wp + (size_t)(s * NF + fbase) * 1024;
        u16* dst = sm + buf * CF * 1024;
#pragma unroll
        for (int c = 0; c < 2 * CF; c += 4) {
            int cc = c + wid;
            if (cc < 2 * CF) gll16(wsrc + cc * 512 + l * 8, dst + cc * 512);
        }
    };
    f32x4 acc[CF] = {};
    stage(0, 0);
    __syncthreads();
    for (int s = 0; s < ns; ++s) {
        if (s + 1 < ns) stage(s + 1, (s + 1) & 1);
        int kb = s * 32 + lk8;
        const u16 *ph, *pl2;
        size_t off;
        if (kb < K1) { ph = A1h; pl2 = A1l; off = (size_t)rowA * ld1 + kb; }
        else { ph = A2h; pl2 = A2l; off = (size_t)rowA * ld2 + (kb - K1); }
        s16x8 ah = *(const s16x8*)(ph + off), al = *(const s16x8*)(pl2 + off);
        const u16* cur = sm + (s & 1) * CF * 1024;
#pragma unroll
        for (int cf = 0; cf < CF; ++cf) {
            s16x8 wh = *(const s16x8*)(cur + cf * 1024 + l * 8);
            s16x8 wl = *(const s16x8*)(cur + cf * 1024 + 512 + l * 8);
            mma3(acc[cf], ah, al, wh, wl);
        }
        __syncthreads();
    }
#pragma unroll
    for (int cf = 0; cf < CF; ++cf) {
        int col = (fbase + cf) * 16 + lr;
        float bv = (b1 ? b1[col] : 0.f) + (b2 ? b2[col] : 0.f);
        f32x4 v4;
#pragma unroll
        for (int r = 0; r < 4; ++r) {
            float v = acc[cf][r] + bv;
            if (ACT) v = tanh_fast(v);
            v4[r] = v;
            int row = row0 + l4 + r;
            if (Oh) split_store(v, Oh, Ol, (size_t)row * ldop + col);
        }
        if (outFrag) *(f32x4*)(outFrag + (size_t)(fragbase + cf) * 256 + l * 4) = v4;
    }
}

// ---------------- direct-load GEMM (small weights) ----------------
template <int CF>
__device__ __forceinline__ void pdirect_gemm(
    int ns, int row0, int fbase,
    const u16* __restrict__ A1h, const u16* __restrict__ A1l, int ld1,
    const u16* __restrict__ Wp, int NF,
    const float* __restrict__ b1, int ACT,
    float* __restrict__ outF, int ldo,
    u16* __restrict__ Oh, u16* __restrict__ Ol, int ldop,
    int l, int lr, int lk8, int l4) {
    const s16x8* wp = (const s16x8*)Wp;
    const int rowA = row0 + lr;
    f32x4 acc[CF] = {};
    for (int s = 0; s < ns; ++s) {
        int kb = s * 32 + lk8;
        size_t off = (size_t)rowA * ld1 + kb;
        s16x8 ah = *(const s16x8*)(A1h + off), al = *(const s16x8*)(A1l + off);
#pragma unroll
        for (int cf = 0; cf < CF; ++cf) {
            int fi = s * NF + fbase + cf;
            mma3(acc[cf], ah, al, wp[fi * 128 + l], wp[fi * 128 + 64 + l]);
        }
    }
#pragma unroll
    for (int cf = 0; cf < CF; ++cf) {
        int col = (fbase + cf) * 16 + lr;
        float bv = b1 ? b1[col] : 0.f;
#pragma unroll
        for (int r = 0; r < 4; ++r) {
            float v = acc[cf][r] + bv;
            if (ACT) v = tanh_fast(v);
            int row = row0 + l4 + r;
            if (outF) outF[(size_t)row * ldo + col] = v;
            if (Oh) split_store(v, Oh, Ol, (size_t)row * ldop + col);
        }
    }
}

// ---------------- the persistent kernel: 512 blocks, 2 per CU ----------------
__global__ __launch_bounds__(256, 2) void vae_persist(AllP P) {
    __shared__ u16 sm[8192];  // 16 KB double-buffered staging
    const int tid = threadIdx.x, b = blockIdx.x;
    const int wid = tid >> 6, l = tid & 63;
    const int lr = l & 15, lk8 = (l >> 4) * 8, l4 = (l >> 4) * 4;
    const int xcd = b & 7, bm = b >> 3;  // 64 blocks per XCD group
    u32 xk = 0;

    // ================= encoder: XCD-local (scan = xcd>>1, row half = xcd&1) =============
    {
        const int scan = xcd >> 1;
        const int rowbase = (xcd & 1) * 512;
        const int T = (scan < 2) ? 64 : 100;
        const int rev = scan & 1;
        const u16* Xb = (scan < 2) ? P.Xh : P.Yh;
        const u16* Xlb = (scan < 2) ? P.Xl : P.Yl;
        const s16x8* wp = (const s16x8*)P.Wenc[scan];
        const float* bi = P.ebi[scan];
        const float* bh = P.ebh[scan];
        u16* Hhb = P.encHh + (size_t)scan * 524288;
        u16* Hlb = P.encHl + (size_t)scan * 524288;
        const int rt = bm >> 3, ct = bm & 7;       // 8 row tiles x 8 col slices
        const int row0 = rowbase + rt * 64 + wid * 16;
        const int rowA = row0 + lr;
        const int hc0 = ct * 32;
        float cst[2][4] = {};
        float hsr[2][4] = {};

        for (int t = 0; t < T; ++t) {
            const int tt = rev ? (T - 1 - t) : t;
            const u16* xh = Xb + (size_t)tt * 65536;
            const u16* xl = Xlb + (size_t)tt * 65536;
            const u16* Hch = Hhb + (size_t)(t & 1) * 262144;
            const u16* Hcl = Hlb + (size_t)(t & 1) * 262144;
            u16* Hnh = Hhb + (size_t)((t + 1) & 1) * 262144;
            u16* Hnl = Hlb + (size_t)((t + 1) & 1) * 262144;
            f32x4 acc[4][2];
#pragma unroll
            for (int q = 0; q < 4; ++q)
#pragma unroll
                for (int cf = 0; cf < 2; ++cf) {
                    int col = q * 256 + hc0 + cf * 16 + lr;
                    float bv = bi[col] + bh[col];
                    acc[q][cf] = (f32x4){bv, bv, bv, bv};
                }
            const int NS = (t == 0) ? 2 : 10;
            for (int s = 0; s < NS; ++s) {
                int kb = s * 32 + lk8;
                const u16 *ph, *pl2;
                size_t off;
                if (kb < 64) { ph = xh; pl2 = xl; off = (size_t)rowA * 64 + kb; }
                else { ph = Hch; pl2 = Hcl; off = (size_t)rowA * 256 + (kb - 64); }
                s16x8 ah = *(const s16x8*)(ph + off), al = *(const s16x8*)(pl2 + off);
#pragma unroll
                for (int q = 0; q < 4; ++q)
#pragma unroll
                    for (int cf = 0; cf < 2; ++cf) {
                        int fi = s * 64 + q * 16 + ct * 2 + cf;
                        mma3(acc[q][cf], ah, al, wp[fi * 128 + l], wp[fi * 128 + 64 + l]);
                    }
            }
#pragma unroll
            for (int cf = 0; cf < 2; ++cf) {
                int hc = hc0 + cf * 16 + lr;
#pragma unroll
                for (int r = 0; r < 4; ++r) {
                    int row = row0 + l4 + r;
                    size_t co = (size_t)row * 256 + hc;
                    float gi = sigf(acc[0][cf][r]);
                    float gf = sigf(acc[1][cf][r]);
                    float gg = tanh_fast(acc[2][cf][r]);
                    float go = sigf(acc[3][cf][r]);
                    float cn = gf * cst[cf][r] + gi * gg;
                    float hn = go * tanh_fast(cn);
                    cst[cf][r] = cn;
                    hsr[cf][r] += hn;
                    split_store(hn, Hnh, Hnl, co);
                }
            }
            barx(P.xflags, xcd, ++xk);
        }
        float sc = (scan < 2) ? (1.f / 64.f) : (1.f / 100.f);
#pragma unroll
        for (int cf = 0; cf < 2; ++cf) {
            int col = scan * 256 + hc0 + cf * 16 + lr;
#pragma unroll
            for (int r = 0; r < 4; ++r) {
                int row = row0 + l4 + r;
                split_store(hsr[cf][r] * sc, P.HXYh, P.HXYl, (size_t)row * 1024 + col);
            }
        }
    }
    barg(P.gflags, 1);  // the ONLY cross-XCD handoff

    // ================= middle (rows xcd*128..+127, all XCD-local) =================
    {
        const int rt = bm & 1, ct = bm >> 1;  // ct 0..31
        pstage_gemm<2>(sm, 32, xcd * 128 + rt * 64 + wid * 16, ct * 2,
                       P.HXYh, P.HXYl, 1024, 4096, nullptr, nullptr, 0,
                       P.Wm1, 64, P.b19, nullptr, 1,
                       nullptr, 0, P.H1h, P.H1l, 1024, wid, l, lr, lk8, l4);
    }
    barx(P.xflags, xcd, ++xk);
    {
        const int rt = bm & 1, ct = bm >> 1;
        pstage_gemm<1>(sm, 32, xcd * 128 + rt * 64 + wid * 16, ct,
                       P.H1h, P.H1l, 1024, 4096, nullptr, nullptr, 0,
                       P.Wm2, 32, P.b21, nullptr, 1,
                       nullptr, 0, P.H2h, P.H2l, 512, wid, l, lr, lk8, l4);
    }
    barx(P.xflags, xcd, ++xk);
    {
        if (bm < 16) {
            const int rt = bm & 1, cfi = bm >> 1;
            pdirect_gemm<1>(16, xcd * 128 + rt * 64 + wid * 16, cfi,
                            P.H2h, P.H2l, 512, P.Wmu, 8, P.b23, 0,
                            P.muF, 128, P.muh, P.mul2, 128, l, lr, lk8, l4);
        } else if (bm < 32) {
            const int bm2 = bm - 16;
            const int rt = bm2 & 1, cfi = bm2 >> 1;
            pdirect_gemm<1>(16, xcd * 128 + rt * 64 + wid * 16, cfi,
                            P.H2h, P.H2l, 512, P.Wlv, 8, P.b25, 0,
                            P.lvF, 128, nullptr, nullptr, 0, l, lr, lk8, l4);
        }
    }
    barx(P.xflags, xcd, ++xk);
    {
        const int rt = bm & 1, ct = bm >> 1;
        const int fragbase = (xcd * 8 + rt * 4 + wid) * 128 + ct * 4;
        pstage_gemm<4>(sm, 20, xcd * 128 + rt * 64 + wid * 16, ct * 4,
                       P.HXYh, P.HXYl, 1024, 512, P.muh, P.mul2, 128,
                       P.Wcg, 128, P.b28, P.b29, 0,
                       P.CGF, fragbase, nullptr, nullptr, 0, wid, l, lr, lk8, l4);
    }
    barx(P.xflags, xcd, ++xk);

    // ================= decoder (rows xcd*128..+127, all XCD-local) =================
    float cds[4] = {};
    for (int t = 0; t < 100; ++t) {
        // ---- gates + cell: rt = bm>>5 (0..1), ct = bm&31 (one frag per gate) ----
        {
            const int rt = bm >> 5, ct = bm & 31;
            const int row0 = xcd * 128 + rt * 64 + wid * 16;
            const int rowA = row0 + lr;
            const int RT = xcd * 8 + rt * 4 + wid;
            const u16* yph = (t == 0) ? (P.Xh + (size_t)63 * 65536) : P.Ydh;
            const u16* ypl = (t == 0) ? (P.Xl + (size_t)63 * 65536) : P.Ydl;
            const u16* Hch = P.decHh + (size_t)(t & 1) * 524288;
            const u16* Hcl = P.decHl + (size_t)(t & 1) * 524288;
            u16* Hnh = P.decHh + (size_t)((t + 1) & 1) * 524288;
            u16* Hnl = P.decHl + (size_t)((t + 1) & 1) * 524288;
            auto stg = [&](int s, int buf) {
                const u16* src = P.Wdg + (size_t)(s * 128 + wid * 32 + ct) * 1024 + l * 8;
                u16* dst = sm + buf * 4096 + wid * 1024;
                gll16(src, dst);
                gll16(src + 512, dst + 512);
            };
            f32x4 acc[4];
#pragma unroll
            for (int q = 0; q < 4; ++q)
                acc[q] = *(const f32x4*)(P.CGF +
                         (size_t)(RT * 128 + q * 32 + ct) * 256 + l * 4);
            const int ns = (t == 0) ? 2 : 18;
            stg(0, 0);
            __syncthreads();
            for (int s = 0; s < ns; ++s) {
                if (s + 1 < ns) stg(s + 1, (s + 1) & 1);
                int kb = s * 32 + lk8;
                const u16 *ph, *pl2;
                size_t off;
                if (kb < 64) { ph = yph; pl2 = ypl; off = (size_t)rowA * 64 + kb; }
                else { ph = Hch; pl2 = Hcl; off = (size_t)rowA * 512 + (kb - 64); }
                s16x8 ah = *(const s16x8*)(ph + off), al = *(const s16x8*)(pl2 + off);
                const u16* cur = sm + (s & 1) * 4096;
#pragma unroll
                for (int q = 0; q < 4; ++q) {
                    s16x8 wh = *(const s16x8*)(cur + q * 1024 + l * 8);
                    s16x8 wl = *(const s16x8*)(cur + q * 1024 + 512 + l * 8);
                    mma3(acc[q], ah, al, wh, wl);
                }
                __syncthreads();
            }
            const int hc = ct * 16 + lr;
#pragma unroll
            for (int r = 0; r < 4; ++r) {
                int row = row0 + l4 + r;
                size_t co = (size_t)row * 512 + hc;
                float gi = sigf(acc[0][r]);
                float gf = sigf(acc[1][r]);
                float gg = tanh_fast(acc[2][r]);
                float go = sigf(acc[3][r]);
                float cold = (t == 0) ? 0.f : cds[r];
                float cn = gf * cold + gi * gg;
                float hn = go * tanh_fast(cn);
                cds[r] = cn;
                split_store(hn, Hnh, Hnl, co);
            }
        }
        barx(P.xflags, xcd, ++xk);
        {
            const u16* Hnh = P.decHh + (size_t)((t + 1) & 1) * 524288;
            const u16* Hnl = P.decHl + (size_t)((t + 1) & 1) * 524288;
            const int rt = bm & 1, ct = bm >> 1;
            pstage_gemm<2>(sm, 16, xcd * 128 + rt * 64 + wid * 16, ct * 2,
                           Hnh, Hnl, 512, 4096, nullptr, nullptr, 0,
                           P.Wd1, 64, P.b31, nullptr, 1,
                           nullptr, 0, P.H1h, P.H1l, 1024, wid, l, lr, lk8, l4);
        }
        barx(P.xflags, xcd, ++xk);
        {
            const int rt = bm & 1, ct = bm >> 1;
            pstage_gemm<1>(sm, 32, xcd * 128 + rt * 64 + wid * 16, ct,
                           P.H1h, P.H1l, 1024, 4096, nullptr, nullptr, 0,
                           P.Wd2, 32, P.b33, nullptr, 1,
                           nullptr, 0, P.H2h, P.H2l, 512, wid, l, lr, lk8, l4);
        }
        barx(P.xflags, xcd, ++xk);
        if (bm < 2)
            pdirect_gemm<4>(16, xcd * 128 + bm * 64 + wid * 16, 0,
                            P.H2h, P.H2l, 512, P.Wdo, 4, P.b35, 0,
                            P.outY + (size_t)t * 65536, 64,
                            P.Ydh, P.Ydl, 64, l, lr, lk8, l4);
        barx(P.xflags, xcd, ++xk);
    }
}

// ---------------- host ----------------
extern "C" void kernel_launch(void* const* d_in, const int* in_sizes, int n_in,
                              void* d_out, int out_size, void* d_ws, size_t ws_size,
                              hipStream_t stream) {
    (void)in_sizes; (void)n_in; (void)out_size; (void)ws_size;
    auto F = [&](int i) { return (const float*)d_in[i]; };
    const float* x = F(0);
    const float* y = F(1);
    float* out = (float*)d_out;
    char* base = (char*)d_ws;
    const size_t MB = 1ull << 20;
    const size_t KB = 1024;

    AllP P;
    P.gflags = (u32*)base;                       // 32 KB (512 x 64B)
    P.xflags = (u32*)(base + 32 * KB);           // 32 KB
    char* p = base + 64 * KB;
    P.CGF = (float*)p; p += 8 * MB;
    P.encHh = (u16*)p; p += 4 * MB;
    P.encHl = (u16*)p; p += 4 * MB;
    P.decHh = (u16*)p; p += 2 * MB;
    P.decHl = (u16*)p; p += 2 * MB;
    P.HXYh = (u16*)p; p += 2 * MB;
    P.HXYl = (u16*)p; p += 2 * MB;
    P.H1h = (u16*)p; p += 2 * MB;
    P.H1l = (u16*)p; p += 2 * MB;
    P.H2h = (u16*)p; p += 1 * MB;
    P.H2l = (u16*)p; p += 1 * MB;
    P.muh = (u16*)p; p += 256 * KB;
    P.mul2 = (u16*)p; p += 256 * KB;
    P.Ydh = (u16*)p; p += 128 * KB;
    P.Ydl = (u16*)p; p += 128 * KB;
    u16* Xh = (u16*)p; p += 8 * MB;
    u16* Xl = (u16*)p; p += 8 * MB;
    u16* Yh = (u16*)p; p += (size_t)100 * 1024 * 64 * 2;
    u16* Yl = (u16*)p; p += (size_t)100 * 1024 * 64 * 2;
    u16* W0 = (u16*)p;

    size_t wo = 0;
    auto walloc = [&](size_t elems) { u16* q = W0 + wo; wo += elems * 2; return q; };
    u16* WPX0 = walloc((size_t)1024 * 320);
    u16* WPX1 = walloc((size_t)1024 * 320);
    u16* WPE0 = walloc((size_t)1024 * 320);
    u16* WPE1 = walloc((size_t)1024 * 320);
    u16* WPM1 = walloc((size_t)1024 * 1024);
    u16* WPM2 = walloc((size_t)512 * 1024);
    u16* WPMU = walloc((size_t)128 * 512);
    u16* WPLV = walloc((size_t)128 * 512);
    u16* WPCG = walloc((size_t)2048 * 640);
    u16* WPDG = walloc((size_t)2048 * 576);
    u16* WPD1 = walloc((size_t)1024 * 512);
    u16* WPD2 = walloc((size_t)512 * 1024);
    u16* WPDO = walloc((size_t)64 * 512);

    auto prep = [&](const float* s1, int ld1, int k1, const float* s2, int ld2,
                    u16* o, int N, int KT) {
        prep_w<<<(N * KT / 8) / 256, 256, 0, stream>>>(s1, ld1, k1, s2, ld2, o, N / 16);
    };
    prep(F(2), 64, 64, F(3), 256, WPX0, 1024, 320);
    prep(F(6), 64, 64, F(7), 256, WPX1, 1024, 320);
    prep(F(10), 64, 64, F(11), 256, WPE0, 1024, 320);
    prep(F(14), 64, 64, F(15), 256, WPE1, 1024, 320);
    prep(F(18), 1024, 1024, F(18), 1024, WPM1, 1024, 1024);
    prep(F(20), 1024, 1024, F(20), 1024, WPM2, 512, 1024);
    prep(F(22), 512, 512, F(22), 512, WPMU, 128, 512);
    prep(F(24), 512, 512, F(24), 512, WPLV, 128, 512);
    prep(F(26), 704, 640, F(26), 704, WPCG, 2048, 640);
    prep(F(26) + 640, 704, 64, F(27), 512, WPDG, 2048, 576);
    prep(F(30), 512, 512, F(30), 512, WPD1, 1024, 512);
    prep(F(32), 1024, 1024, F(32), 1024, WPD2, 512, 1024);
    prep(F(34), 512, 512, F(34), 512, WPDO, 64, 512);

    prep_act<<<4096, 256, 0, stream>>>(x, Xh, Xl, 64 * 1024 * 64 / 4);
    prep_act<<<6400, 256, 0, stream>>>(y, Yh, Yl, 100 * 1024 * 64 / 4);

    hipMemsetAsync(base, 0, 64 * KB, stream);  // barrier flags only

    P.Xh = Xh; P.Xl = Xl; P.Yh = Yh; P.Yl = Yl;
    const int wi[4] = {2, 6, 10, 14};
    u16* wps[4] = {WPX0, WPX1, WPE0, WPE1};
    for (int s = 0; s < 4; ++s) {
        P.Wenc[s] = wps[s];
        P.ebi[s] = F(wi[s] + 2);
        P.ebh[s] = F(wi[s] + 3);
    }
    P.Wm1 = WPM1; P.Wm2 = WPM2; P.Wmu = WPMU; P.Wlv = WPLV;
    P.Wcg = WPCG; P.Wdg = WPDG; P.Wd1 = WPD1; P.Wd2 = WPD2; P.Wdo = WPDO;
    P.b19 = F(19); P.b21 = F(21); P.b23 = F(23); P.b25 = F(25);
    P.b28 = F(28); P.b29 = F(29); P.b31 = F(31); P.b33 = F(33); P.b35 = F(35);
    P.outY = out;
    P.muF = out + (size_t)100 * 1024 * 64;
    P.lvF = P.muF + (size_t)1024 * 128;

    vae_persist<<<512, 256, 0, stream>>>(P);
}